// Round 1
// baseline (716.785 us; speedup 1.0000x reference)
//
#include <hip/hip_runtime.h>
#include <math.h>

#ifndef M_PI
#define M_PI 3.14159265358979323846
#endif

// Problem constants
// inputs: (8192, 512) f32 ; channel_angles (2,7) ; kernel_angles (2,4)
// channel_entangle (2048,2048) f32 ; kernel_entangle (2048,2048) f32
// out: (8192,) f32
//
// Math: out[b] = (x_b^T Ghat x_b) / (4 * mag_b),  mag = sqrt(sum x^2)+1e-7
// Ghat = (M E)^T diag(parity) (M E),   M = c@ch0@c@k@kr0@ch1@c@k@kr1@k (all real)
// E: 2048->512 replication map  p(n) = (((n>>5)*16) + (n&15)) >> 1

// ---------------- build rotation matrices ----------------
__global__ void build_rots_kernel(const float* __restrict__ ch_ang,
                                  const float* __restrict__ k_ang,
                                  float* __restrict__ C128,   // 2 x 128 x 128
                                  float* __restrict__ K16)    // 2 x 16 x 16
{
    int tid = blockIdx.x * blockDim.x + threadIdx.x;
    int stride = gridDim.x * blockDim.x;
    for (int idx = tid; idx < 2 * 128 * 128; idx += stride) {
        int l = idx >> 14;
        int rem = idx & 16383;
        int a = rem >> 7, b = rem & 127;
        float p = 1.0f;
#pragma unroll
        for (int q = 0; q < 7; ++q) {
            float half = ch_ang[l * 7 + q] * (float)M_PI;  // theta = ang*2pi, half = ang*pi
            float c = cosf(half), s = sinf(half);
            int ia = (a >> (6 - q)) & 1;
            int ib = (b >> (6 - q)) & 1;
            float e = ia ? (ib ? c : s) : (ib ? -s : c);   // Ry = [[c,-s],[s,c]]
            p *= e;
        }
        C128[idx] = p;
    }
    for (int idx = tid; idx < 2 * 16 * 16; idx += stride) {
        int l = idx >> 8;
        int rem = idx & 255;
        int a = rem >> 4, b = rem & 15;
        float p = 1.0f;
#pragma unroll
        for (int q = 0; q < 4; ++q) {
            float half = k_ang[l * 4 + q] * 0.5f;          // theta = ang, half = ang/2
            float c = cosf(half), s = sinf(half);
            int ia = (a >> (3 - q)) & 1;
            int ib = (b >> (3 - q)) & 1;
            float e = ia ? (ib ? c : s) : (ib ? -s : c);
            p *= e;
        }
        K16[idx] = p;
    }
}

// ---------------- T = k_ent @ E  (column collapse) ----------------
__global__ __launch_bounds__(256) void collapse_kernel(const float* __restrict__ kent,
                                                       float* __restrict__ T)
{
    int idx = blockIdx.x * blockDim.x + threadIdx.x;  // n*512 + s
    if (idx >= 2048 * 512) return;
    int n = idx >> 9, s = idx & 511;
    const float* row = kent + (size_t)n * 2048;
    float acc = 0.0f;
#pragma unroll
    for (int dj = 0; dj < 2; ++dj) {
        int j = 2 * s + dj;
        int m0 = ((j >> 4) << 5) | (j & 15);
        acc += row[m0] + row[m0 + 16];
    }
    T[idx] = acc;
}

// ---------------- apply k_rot (mix last 16 rows), in place ----------------
__global__ __launch_bounds__(512) void krot_kernel(const float* __restrict__ K16l,
                                                   float* __restrict__ T)
{
    int s = threadIdx.x;  // one column per thread; columns independent
    float vals[16];
#pragma unroll
    for (int r = 0; r < 16; ++r) vals[r] = T[(size_t)(2032 + r) * 512 + s];
    float k[16 * 16];
#pragma unroll
    for (int i = 0; i < 256; ++i) k[i] = K16l[i];
#pragma unroll
    for (int r = 0; r < 16; ++r) {
        float a = 0.0f;
#pragma unroll
        for (int rp = 0; rp < 16; ++rp) a += k[r * 16 + rp] * vals[rp];
        T[(size_t)(2032 + r) * 512 + s] = a;
    }
}

// ---------------- generic fp32 GEMM: C[M,N] = A[M,K] @ B[K,N] ----------------
// BM=64 BN=64 BK=32, 256 threads, 4x4 per thread. grid = (M/64, N/64)
__global__ __launch_bounds__(256) void gemm_fp32(const float* __restrict__ A,
                                                 const float* __restrict__ B,
                                                 float* __restrict__ C,
                                                 int N, int K)
{
    __shared__ __align__(16) float sA[32][68];  // sA[k][m], pad 68 keeps float4 alignment
    __shared__ __align__(16) float sB[32][68];  // sB[k][n]
    int bm = blockIdx.x, bn = blockIdx.y;
    int tid = threadIdx.x;
    int tx = tid & 15, ty = tid >> 4;
    float acc[4][4] = {};

    for (int kt = 0; kt < K; kt += 32) {
        // A tile: 64 rows x 32 cols -> transpose to sA[k][m]
#pragma unroll
        for (int i = 0; i < 2; ++i) {
            int lin = tid + i * 256;        // 0..511 float4 slots
            int r = lin >> 3;               // 8 float4 per row of 32
            int c4 = lin & 7;
            float4 av = *reinterpret_cast<const float4*>(
                &A[(size_t)(bm * 64 + r) * K + kt + c4 * 4]);
            sA[c4 * 4 + 0][r] = av.x;
            sA[c4 * 4 + 1][r] = av.y;
            sA[c4 * 4 + 2][r] = av.z;
            sA[c4 * 4 + 3][r] = av.w;
        }
        // B tile: 32 rows x 64 cols direct
#pragma unroll
        for (int i = 0; i < 2; ++i) {
            int lin = tid + i * 256;
            int r = lin >> 4;               // 16 float4 per row of 64
            int c4 = lin & 15;
            float4 bv = *reinterpret_cast<const float4*>(
                &B[(size_t)(kt + r) * N + bn * 64 + c4 * 4]);
            *reinterpret_cast<float4*>(&sB[r][c4 * 4]) = bv;
        }
        __syncthreads();
#pragma unroll
        for (int k = 0; k < 32; ++k) {
            float4 a = *reinterpret_cast<const float4*>(&sA[k][ty * 4]);
            float4 b = *reinterpret_cast<const float4*>(&sB[k][tx * 4]);
            acc[0][0] += a.x * b.x; acc[0][1] += a.x * b.y; acc[0][2] += a.x * b.z; acc[0][3] += a.x * b.w;
            acc[1][0] += a.y * b.x; acc[1][1] += a.y * b.y; acc[1][2] += a.y * b.z; acc[1][3] += a.y * b.w;
            acc[2][0] += a.z * b.x; acc[2][1] += a.z * b.y; acc[2][2] += a.z * b.z; acc[2][3] += a.z * b.w;
            acc[3][0] += a.w * b.x; acc[3][1] += a.w * b.y; acc[3][2] += a.w * b.z; acc[3][3] += a.w * b.w;
        }
        __syncthreads();
    }
#pragma unroll
    for (int i = 0; i < 4; ++i) {
        float4 v = make_float4(acc[i][0], acc[i][1], acc[i][2], acc[i][3]);
        *reinterpret_cast<float4*>(
            &C[(size_t)(bm * 64 + ty * 4 + i) * N + bn * 64 + tx * 4]) = v;
    }
}

// ---------------- Ghat[s,t] = sum_n parity(n) * T[n,s] * T[n,t] ----------------
__global__ __launch_bounds__(256) void ghat_kernel(const float* __restrict__ T,
                                                   float* __restrict__ G)
{
    __shared__ __align__(16) float sS[32][68];
    __shared__ __align__(16) float sT[32][68];
    int bs = blockIdx.x, bt = blockIdx.y;
    int tid = threadIdx.x;
    int tx = tid & 15, ty = tid >> 4;
    float acc[4][4] = {};

    for (int n0 = 0; n0 < 2048; n0 += 32) {
#pragma unroll
        for (int i = 0; i < 2; ++i) {
            int lin = tid + i * 256;
            int r = lin >> 4;
            int c4 = lin & 15;
            int n = n0 + r;
            float4 v1 = *reinterpret_cast<const float4*>(
                &T[(size_t)n * 512 + bs * 64 + c4 * 4]);
            *reinterpret_cast<float4*>(&sS[r][c4 * 4]) = v1;
            float4 v2 = *reinterpret_cast<const float4*>(
                &T[(size_t)n * 512 + bt * 64 + c4 * 4]);
            float p = 1.0f - 2.0f * (float)(__popc(n) & 1);
            v2.x *= p; v2.y *= p; v2.z *= p; v2.w *= p;
            *reinterpret_cast<float4*>(&sT[r][c4 * 4]) = v2;
        }
        __syncthreads();
#pragma unroll
        for (int k = 0; k < 32; ++k) {
            float4 a = *reinterpret_cast<const float4*>(&sS[k][ty * 4]);
            float4 b = *reinterpret_cast<const float4*>(&sT[k][tx * 4]);
            acc[0][0] += a.x * b.x; acc[0][1] += a.x * b.y; acc[0][2] += a.x * b.z; acc[0][3] += a.x * b.w;
            acc[1][0] += a.y * b.x; acc[1][1] += a.y * b.y; acc[1][2] += a.y * b.z; acc[1][3] += a.y * b.w;
            acc[2][0] += a.z * b.x; acc[2][1] += a.z * b.y; acc[2][2] += a.z * b.z; acc[2][3] += a.z * b.w;
            acc[3][0] += a.w * b.x; acc[3][1] += a.w * b.y; acc[3][2] += a.w * b.z; acc[3][3] += a.w * b.w;
        }
        __syncthreads();
    }
#pragma unroll
    for (int i = 0; i < 4; ++i) {
        float4 v = make_float4(acc[i][0], acc[i][1], acc[i][2], acc[i][3]);
        *reinterpret_cast<float4*>(
            &G[(size_t)(bs * 64 + ty * 4 + i) * 512 + bt * 64 + tx * 4]) = v;
    }
}

// ---------------- out[b] = (x^T G x) / (4*mag) ----------------
// block = 256 threads, 8 batch rows per block
__global__ __launch_bounds__(256) void final_kernel(const float* __restrict__ X,
                                                    const float* __restrict__ G,
                                                    float* __restrict__ out)
{
    __shared__ __align__(16) float xs[8][512];
    __shared__ float mags[8];
    __shared__ float wsum[4][8];
    int b0 = blockIdx.x * 8;
    int tid = threadIdx.x;

    // load 8x512 floats
#pragma unroll
    for (int i = 0; i < 4; ++i) {
        int lin = tid + i * 256;      // 0..1023 float4 slots
        int r = lin >> 7;             // 128 float4 per row
        int c4 = lin & 127;
        float4 v = *reinterpret_cast<const float4*>(&X[(size_t)(b0 + r) * 512 + c4 * 4]);
        *reinterpret_cast<float4*>(&xs[r][c4 * 4]) = v;
    }
    __syncthreads();

    // per-row sumsq (32 threads per row)
    {
        int r = tid >> 5, ln = tid & 31;
        float ss = 0.0f;
        for (int j = ln; j < 512; j += 32) {
            float v = xs[r][j];
            ss += v * v;
        }
#pragma unroll
        for (int off = 16; off; off >>= 1) ss += __shfl_xor(ss, off, 64);
        if (ln == 0) mags[r] = sqrtf(ss) + 1e-7f;
    }
    __syncthreads();

    // each thread owns columns t = tid and tid+256
    float xt0[8], xt1[8];
#pragma unroll
    for (int r = 0; r < 8; ++r) {
        xt0[r] = xs[r][tid];
        xt1[r] = xs[r][tid + 256];
    }
    float acc[8] = {};
    for (int s = 0; s < 512; ++s) {
        float g0 = G[(size_t)s * 512 + tid];
        float g1 = G[(size_t)s * 512 + tid + 256];
#pragma unroll
        for (int r = 0; r < 8; ++r) {
            acc[r] += (g0 * xt0[r] + g1 * xt1[r]) * xs[r][s];
        }
    }

    // reduce across the block
#pragma unroll
    for (int r = 0; r < 8; ++r) {
#pragma unroll
        for (int off = 32; off; off >>= 1) acc[r] += __shfl_xor(acc[r], off, 64);
    }
    int wv = tid >> 6, ln = tid & 63;
    if (ln == 0) {
#pragma unroll
        for (int r = 0; r < 8; ++r) wsum[wv][r] = acc[r];
    }
    __syncthreads();
    if (tid < 8) {
        float s = wsum[0][tid] + wsum[1][tid] + wsum[2][tid] + wsum[3][tid];
        out[b0 + tid] = s / (4.0f * mags[tid]);
    }
}

extern "C" void kernel_launch(void* const* d_in, const int* in_sizes, int n_in,
                              void* d_out, int out_size, void* d_ws, size_t ws_size,
                              hipStream_t stream)
{
    const float* X     = (const float*)d_in[0];
    const float* chang = (const float*)d_in[1];
    const float* kang  = (const float*)d_in[2];
    const float* cent  = (const float*)d_in[3];
    const float* kent  = (const float*)d_in[4];
    float* out = (float*)d_out;

    float* ws   = (float*)d_ws;
    float* Ta   = ws;                      // 2048*512
    float* Tb   = Ta + 2048 * 512;         // 2048*512
    float* G    = Tb + 2048 * 512;         // 512*512
    float* C128 = G + 512 * 512;           // 2*128*128
    float* K16  = C128 + 2 * 128 * 128;    // 2*16*16

    build_rots_kernel<<<64, 256, 0, stream>>>(chang, kang, C128, K16);

    // chain right-to-left: matrix = c @ ch0 @ c @ k @ kr0 @ ch1 @ c @ k @ kr1 @ k, applied to E
    collapse_kernel<<<(2048 * 512) / 256, 256, 0, stream>>>(kent, Ta);     // Ta = k_ent @ E
    krot_kernel<<<1, 512, 0, stream>>>(K16 + 256, Ta);                     // kr1 (layer 1)
    gemm_fp32<<<dim3(32, 8), 256, 0, stream>>>(kent, Ta, Tb, 512, 2048);   // Tb = k_ent @ Ta
    gemm_fp32<<<dim3(32, 8), 256, 0, stream>>>(cent, Tb, Ta, 512, 2048);   // Ta = c_ent @ Tb
    gemm_fp32<<<dim3(2, 128), 256, 0, stream>>>(C128 + 16384, Ta, Tb, 8192, 128); // ch1: Tb = (C128_1 (x) I16) @ Ta
    krot_kernel<<<1, 512, 0, stream>>>(K16, Tb);                           // kr0 (layer 0)
    gemm_fp32<<<dim3(32, 8), 256, 0, stream>>>(kent, Tb, Ta, 512, 2048);   // Ta = k_ent @ Tb
    gemm_fp32<<<dim3(32, 8), 256, 0, stream>>>(cent, Ta, Tb, 512, 2048);   // Tb = c_ent @ Ta
    gemm_fp32<<<dim3(2, 128), 256, 0, stream>>>(C128, Tb, Ta, 8192, 128);  // ch0: Ta = (C128_0 (x) I16) @ Tb
    gemm_fp32<<<dim3(32, 8), 256, 0, stream>>>(cent, Ta, Tb, 512, 2048);   // Tb = c_ent @ Ta  (= M @ E)

    ghat_kernel<<<dim3(8, 8), 256, 0, stream>>>(Tb, G);                    // G = (ME)^T diag(par) (ME)
    final_kernel<<<8192 / 8, 256, 0, stream>>>(X, G, out);                 // out = x^T G x / (4*mag)
}

// Round 2
// 244.783 us; speedup vs baseline: 2.9282x; 2.9282x over previous
//
#include <hip/hip_runtime.h>
#include <math.h>

#ifndef M_PI
#define M_PI 3.14159265358979323846
#endif

// out[b] = (x_b^T Ghat x_b) / (4 * mag_b),  mag = sqrt(sum x^2)+1e-7
// Ghat = (M E)^T diag(parity) (M E),  M = c@ch0@c@k@kr0@ch1@c@k@kr1@k (all real)
// Chain is applied right-to-left to E (2048->512 replication map), keeping
// T transposed as Tt[512][2048].  Dense 2048^2 @ 2048x512 products run as
// bf16 hi/lo split MFMA (3 products) with fp32 accumulate.

typedef __attribute__((ext_vector_type(8))) short bf16x8;
typedef __attribute__((ext_vector_type(16))) float f32x16;

// ---------------- helpers ----------------
__device__ __forceinline__ unsigned short bf16_rne(float f) {
    unsigned u = __float_as_uint(f);
    unsigned r = u + 0x7FFFu + ((u >> 16) & 1u);
    return (unsigned short)(r >> 16);
}
__device__ __forceinline__ void split2(float f, unsigned short& h, unsigned short& l) {
    h = bf16_rne(f);
    float fh = __uint_as_float(((unsigned)h) << 16);
    l = bf16_rne(f - fh);
}
__device__ __forceinline__ void async_copy16(const void* gsrc, void* ldst) {
    __builtin_amdgcn_global_load_lds(
        (const __attribute__((address_space(1))) unsigned int*)gsrc,
        (__attribute__((address_space(3))) unsigned int*)ldst,
        16, 0, 0);
}

// ---------------- build rotation matrices ----------------
__global__ void build_rots_kernel(const float* __restrict__ ch_ang,
                                  const float* __restrict__ k_ang,
                                  float* __restrict__ C128,   // 2 x 128 x 128
                                  float* __restrict__ K16)    // 2 x 16 x 16
{
    int tid = blockIdx.x * blockDim.x + threadIdx.x;
    int stride = gridDim.x * blockDim.x;
    for (int idx = tid; idx < 2 * 128 * 128; idx += stride) {
        int l = idx >> 14;
        int rem = idx & 16383;
        int a = rem >> 7, b = rem & 127;
        float p = 1.0f;
#pragma unroll
        for (int q = 0; q < 7; ++q) {
            float half = ch_ang[l * 7 + q] * (float)M_PI;
            float c = cosf(half), s = sinf(half);
            int ia = (a >> (6 - q)) & 1;
            int ib = (b >> (6 - q)) & 1;
            float e = ia ? (ib ? c : s) : (ib ? -s : c);
            p *= e;
        }
        C128[idx] = p;
    }
    for (int idx = tid; idx < 2 * 16 * 16; idx += stride) {
        int l = idx >> 8;
        int rem = idx & 255;
        int a = rem >> 4, b = rem & 15;
        float p = 1.0f;
#pragma unroll
        for (int q = 0; q < 4; ++q) {
            float half = k_ang[l * 4 + q] * 0.5f;
            float c = cosf(half), s = sinf(half);
            int ia = (a >> (3 - q)) & 1;
            int ib = (b >> (3 - q)) & 1;
            float e = ia ? (ib ? c : s) : (ib ? -s : c);
            p *= e;
        }
        K16[idx] = p;
    }
}

// ---------------- T0 = k_ent @ E  (column collapse), T layout [2048][512] ----------------
__global__ __launch_bounds__(256) void collapse_kernel(const float* __restrict__ kent,
                                                       float* __restrict__ T)
{
    int idx = blockIdx.x * blockDim.x + threadIdx.x;
    if (idx >= 2048 * 512) return;
    int n = idx >> 9, s = idx & 511;
    const float* row = kent + (size_t)n * 2048;
    float acc = 0.0f;
#pragma unroll
    for (int dj = 0; dj < 2; ++dj) {
        int j = 2 * s + dj;
        int m0 = ((j >> 4) << 5) | (j & 15);
        acc += row[m0] + row[m0 + 16];
    }
    T[idx] = acc;
}

// ---------------- k_rot on T layout (rows 2032..2047) ----------------
__global__ __launch_bounds__(512) void krot_kernel(const float* __restrict__ K16l,
                                                   float* __restrict__ T)
{
    int s = threadIdx.x;
    float vals[16];
#pragma unroll
    for (int r = 0; r < 16; ++r) vals[r] = T[(size_t)(2032 + r) * 512 + s];
    float k[256];
#pragma unroll
    for (int i = 0; i < 256; ++i) k[i] = K16l[i];
#pragma unroll
    for (int r = 0; r < 16; ++r) {
        float a = 0.0f;
#pragma unroll
        for (int rp = 0; rp < 16; ++rp) a += k[r * 16 + rp] * vals[rp];
        T[(size_t)(2032 + r) * 512 + s] = a;
    }
}

// ---------------- k_rot on Tt layout (cols 2032..2047 contiguous per row) ----------------
__global__ __launch_bounds__(256) void krot_t_kernel(const float* __restrict__ K16l,
                                                     float* __restrict__ Tt)
{
    int s = blockIdx.x * 256 + threadIdx.x;
    if (s >= 512) return;
    float v[16], o[16];
    float* base = &Tt[(size_t)s * 2048 + 2032];
#pragma unroll
    for (int q = 0; q < 4; ++q) {
        float4 x = *(float4*)&base[q * 4];
        v[q * 4 + 0] = x.x; v[q * 4 + 1] = x.y; v[q * 4 + 2] = x.z; v[q * 4 + 3] = x.w;
    }
#pragma unroll
    for (int r = 0; r < 16; ++r) {
        float a = 0.0f;
#pragma unroll
        for (int rp = 0; rp < 16; ++rp) a += K16l[r * 16 + rp] * v[rp];
        o[r] = a;
    }
#pragma unroll
    for (int q = 0; q < 4; ++q)
        *(float4*)&base[q * 4] = make_float4(o[q * 4], o[q * 4 + 1], o[q * 4 + 2], o[q * 4 + 3]);
}

// ---------------- transpose T[2048][512] f32 -> Tt hi/lo bf16 [512][2048] ----------------
__global__ __launch_bounds__(256) void transpose_convert_kernel(const float* __restrict__ T,
                                                                unsigned short* __restrict__ Hi,
                                                                unsigned short* __restrict__ Lo)
{
    __shared__ float tile[64][65];
    int n0 = blockIdx.x * 64, s0 = blockIdx.y * 64;
    int tid = threadIdx.x;
#pragma unroll
    for (int p = 0; p < 4; ++p) {
        int lin = tid + p * 256;
        int r = lin >> 4, c4 = lin & 15;
        float4 v = *(const float4*)&T[(size_t)(n0 + r) * 512 + s0 + c4 * 4];
        tile[r][c4 * 4 + 0] = v.x; tile[r][c4 * 4 + 1] = v.y;
        tile[r][c4 * 4 + 2] = v.z; tile[r][c4 * 4 + 3] = v.w;
    }
    __syncthreads();
#pragma unroll
    for (int p = 0; p < 4; ++p) {
        int lin = tid + p * 256;
        int sl = lin >> 4, j4 = lin & 15;
        unsigned short h[4], l[4];
#pragma unroll
        for (int q = 0; q < 4; ++q) split2(tile[j4 * 4 + q][sl], h[q], l[q]);
        size_t o = (size_t)(s0 + sl) * 2048 + n0 + j4 * 4;
        *(uint2*)&Hi[o] = make_uint2((unsigned)h[0] | ((unsigned)h[1] << 16),
                                     (unsigned)h[2] | ((unsigned)h[3] << 16));
        *(uint2*)&Lo[o] = make_uint2((unsigned)l[0] | ((unsigned)l[1] << 16),
                                     (unsigned)l[2] | ((unsigned)l[3] << 16));
    }
}

// ---------------- reduce split-K partials + convert (+ optional parity copy) ----------------
// Also used as pure converter (nchunks=1): entprep / xprep / convert_t.
__global__ __launch_bounds__(256) void reduce_hl_kernel(const float* __restrict__ P, int nchunks, int csize,
                                                        float* __restrict__ outF,
                                                        unsigned short* __restrict__ outH,
                                                        unsigned short* __restrict__ outL,
                                                        unsigned short* __restrict__ outPH,
                                                        unsigned short* __restrict__ outPL,
                                                        int rowMask)
{
    int i4 = blockIdx.x * 256 + threadIdx.x;
    size_t base = (size_t)i4 * 4;
    float4 v = *(const float4*)&P[base];
    for (int c = 1; c < nchunks; ++c) {
        float4 u = *(const float4*)&P[(size_t)c * csize + base];
        v.x += u.x; v.y += u.y; v.z += u.z; v.w += u.w;
    }
    if (outF) *(float4*)&outF[base] = v;
    float f[4] = {v.x, v.y, v.z, v.w};
    unsigned short h[4], l[4];
#pragma unroll
    for (int q = 0; q < 4; ++q) split2(f[q], h[q], l[q]);
    if (outH) {
        *(uint2*)&outH[base] = make_uint2((unsigned)h[0] | ((unsigned)h[1] << 16),
                                          (unsigned)h[2] | ((unsigned)h[3] << 16));
        *(uint2*)&outL[base] = make_uint2((unsigned)l[0] | ((unsigned)l[1] << 16),
                                          (unsigned)l[2] | ((unsigned)l[3] << 16));
    }
    if (outPH) {
        unsigned short ph[4], pl[4];
#pragma unroll
        for (int q = 0; q < 4; ++q) {
            int n = (int)((base + q) & (size_t)rowMask);
            unsigned flip = ((unsigned)(__popc(n) & 1)) << 15;
            ph[q] = h[q] ^ (unsigned short)flip;
            pl[q] = l[q] ^ (unsigned short)flip;
        }
        *(uint2*)&outPH[base] = make_uint2((unsigned)ph[0] | ((unsigned)ph[1] << 16),
                                           (unsigned)ph[2] | ((unsigned)ph[3] << 16));
        *(uint2*)&outPL[base] = make_uint2((unsigned)pl[0] | ((unsigned)pl[1] << 16),
                                           (unsigned)pl[2] | ((unsigned)pl[3] << 16));
    }
}

// ---------------- hi/lo split bf16 MFMA GEMM ----------------
// C[M,N] (+= over blockIdx.z chunks) = A[M,K] @ B^T[N,K]  (B given row-major over N, k contiguous)
// 64x64 block tile, 4 waves split over k (16 k each per 64-k step), mfma_32x32x16.
// OUT_TRANS=1: Cout[kc][n*M + m]  (transposed partials);  OUT_TRANS=0: Cout[m*N + n].
template<int OUT_TRANS>
__global__ __launch_bounds__(256) void gemm_hl_kernel(
    const unsigned short* __restrict__ Ahi, const unsigned short* __restrict__ Alo, int ldA,
    const unsigned short* __restrict__ Bhi, const unsigned short* __restrict__ Blo, int ldB,
    float* __restrict__ Cout, int M, int N, int Kchunk)
{
    __shared__ __align__(16) char smem[32768];  // Ah | Al | Bh | Bl, 8KB each
    const int tid = threadIdx.x;
    const int lane = tid & 63;
    const int w = tid >> 6;
    const int bm = blockIdx.x, bn = blockIdx.y, kc = blockIdx.z;
    const int kbase = kc * Kchunk;

    f32x16 acc[2][2];
#pragma unroll
    for (int i = 0; i < 2; ++i)
#pragma unroll
        for (int j = 0; j < 2; ++j)
#pragma unroll
            for (int q = 0; q < 16; ++q) acc[i][j][q] = 0.0f;

    const int col = lane & 31;
    const int hi = lane >> 5;
    const int k16 = w * 16;
    int aaddr[2], baddr[2];
#pragma unroll
    for (int ms = 0; ms < 2; ++ms) {
        int row = ms * 32 + col;
        int cb = (k16 + hi * 8) * 2;
        aaddr[ms] = row * 128 + (cb ^ ((row & 7) << 4));
        baddr[ms] = aaddr[ms];
    }
    // staging precompute (per pass p: slot = p*4096 + tid*16)
    int srow[2], sge[2], sdst[2];
#pragma unroll
    for (int p = 0; p < 2; ++p) {
        int slot = p * 4096 + tid * 16;
        int r = slot >> 7;
        int pc = slot & 127;
        int lc = pc ^ ((r & 7) << 4);
        srow[p] = r;
        sge[p] = lc >> 1;
        sdst[p] = p * 4096 + w * 1024;
    }

    const int nsteps = Kchunk >> 6;
    for (int kt = 0; kt < nsteps; ++kt) {
        int kg = kbase + (kt << 6);
#pragma unroll
        for (int p = 0; p < 2; ++p) {
            int ge = kg + sge[p];
            const unsigned short* a0 = Ahi + (size_t)(bm * 64 + srow[p]) * ldA + ge;
            const unsigned short* a1 = Alo + (size_t)(bm * 64 + srow[p]) * ldA + ge;
            const unsigned short* b0 = Bhi + (size_t)(bn * 64 + srow[p]) * ldB + ge;
            const unsigned short* b1 = Blo + (size_t)(bn * 64 + srow[p]) * ldB + ge;
            async_copy16(a0, &smem[0 + sdst[p]]);
            async_copy16(a1, &smem[8192 + sdst[p]]);
            async_copy16(b0, &smem[16384 + sdst[p]]);
            async_copy16(b1, &smem[24576 + sdst[p]]);
        }
        __syncthreads();
        bf16x8 ah[2], al[2], bh[2], bl[2];
#pragma unroll
        for (int ms = 0; ms < 2; ++ms) {
            ah[ms] = *(const bf16x8*)&smem[0 + aaddr[ms]];
            al[ms] = *(const bf16x8*)&smem[8192 + aaddr[ms]];
        }
#pragma unroll
        for (int ns = 0; ns < 2; ++ns) {
            bh[ns] = *(const bf16x8*)&smem[16384 + baddr[ns]];
            bl[ns] = *(const bf16x8*)&smem[24576 + baddr[ns]];
        }
#pragma unroll
        for (int ms = 0; ms < 2; ++ms)
#pragma unroll
            for (int ns = 0; ns < 2; ++ns) {
                acc[ms][ns] = __builtin_amdgcn_mfma_f32_32x32x16_bf16(ah[ms], bh[ns], acc[ms][ns], 0, 0, 0);
                acc[ms][ns] = __builtin_amdgcn_mfma_f32_32x32x16_bf16(ah[ms], bl[ns], acc[ms][ns], 0, 0, 0);
                acc[ms][ns] = __builtin_amdgcn_mfma_f32_32x32x16_bf16(al[ms], bh[ns], acc[ms][ns], 0, 0, 0);
            }
        __syncthreads();
    }

    // cross-wave k-split tree reduction through LDS
    float* red = (float*)smem;
    if (w >= 2) {
        float* dst = red + (w - 2) * 4096;
#pragma unroll
        for (int ms = 0; ms < 2; ++ms)
#pragma unroll
            for (int ns = 0; ns < 2; ++ns)
#pragma unroll
                for (int r = 0; r < 16; ++r) {
                    int rowr = (r & 3) + 8 * (r >> 2) + 4 * hi;
                    dst[(ms * 32 + rowr) * 64 + ns * 32 + col] = acc[ms][ns][r];
                }
    }
    __syncthreads();
    if (w < 2) {
        float* src = red + w * 4096;
#pragma unroll
        for (int ms = 0; ms < 2; ++ms)
#pragma unroll
            for (int ns = 0; ns < 2; ++ns)
#pragma unroll
                for (int r = 0; r < 16; ++r) {
                    int rowr = (r & 3) + 8 * (r >> 2) + 4 * hi;
                    acc[ms][ns][r] += src[(ms * 32 + rowr) * 64 + ns * 32 + col];
                }
    }
    __syncthreads();
    if (w == 1) {
#pragma unroll
        for (int ms = 0; ms < 2; ++ms)
#pragma unroll
            for (int ns = 0; ns < 2; ++ns)
#pragma unroll
                for (int r = 0; r < 16; ++r) {
                    int rowr = (r & 3) + 8 * (r >> 2) + 4 * hi;
                    red[(ms * 32 + rowr) * 64 + ns * 32 + col] = acc[ms][ns][r];
                }
    }
    __syncthreads();
    if (w == 0) {
#pragma unroll
        for (int ms = 0; ms < 2; ++ms)
#pragma unroll
            for (int ns = 0; ns < 2; ++ns)
#pragma unroll
                for (int r = 0; r < 16; ++r) {
                    int rowr = (r & 3) + 8 * (r >> 2) + 4 * hi;
                    acc[ms][ns][r] += red[(ms * 32 + rowr) * 64 + ns * 32 + col];
                }
        if (OUT_TRANS) {
            float* Cb = Cout + (size_t)kc * M * N;
#pragma unroll
            for (int ms = 0; ms < 2; ++ms)
#pragma unroll
                for (int ns = 0; ns < 2; ++ns)
#pragma unroll
                    for (int g = 0; g < 4; ++g) {
                        int rowt = ms * 32 + 8 * g + 4 * hi;
                        float4 v = make_float4(acc[ms][ns][4 * g + 0], acc[ms][ns][4 * g + 1],
                                               acc[ms][ns][4 * g + 2], acc[ms][ns][4 * g + 3]);
                        *(float4*)&Cb[(size_t)(bn * 64 + ns * 32 + col) * M + bm * 64 + rowt] = v;
                    }
        } else {
#pragma unroll
            for (int ms = 0; ms < 2; ++ms)
#pragma unroll
                for (int ns = 0; ns < 2; ++ns)
#pragma unroll
                    for (int g = 0; g < 4; ++g) {
                        int rowt = ms * 32 + 8 * g + 4 * hi;
#pragma unroll
                        for (int q = 0; q < 4; ++q)
                            Cout[(size_t)(bm * 64 + rowt + q) * N + bn * 64 + ns * 32 + col] =
                                acc[ms][ns][4 * g + q];
                    }
        }
    }
}

// ---------------- channel rotation on Tt: out[s][16a+t] = sum_a' C[a][a'] in[s][16a'+t] ----------------
__global__ __launch_bounds__(256) void chrot_t_kernel(const float* __restrict__ C,
                                                      const float* __restrict__ in,
                                                      float* __restrict__ outp)
{
    __shared__ float row[2048];
    int s = blockIdx.x;
    int tid = threadIdx.x;
    for (int i = tid; i < 512; i += 256) {
        float4 v = *(const float4*)&in[(size_t)s * 2048 + i * 4];
        *(float4*)&row[i * 4] = v;
    }
    __syncthreads();
    int a = tid >> 1, th = (tid & 1) * 8;
    float res[8];
#pragma unroll
    for (int j = 0; j < 8; ++j) res[j] = 0.0f;
    for (int ap = 0; ap < 128; ++ap) {
        float c = C[a * 128 + ap];
#pragma unroll
        for (int j = 0; j < 8; ++j) res[j] += c * row[ap * 16 + th + j];
    }
#pragma unroll
    for (int q = 0; q < 2; ++q)
        *(float4*)&outp[(size_t)s * 2048 + a * 16 + th + q * 4] =
            make_float4(res[q * 4], res[q * 4 + 1], res[q * 4 + 2], res[q * 4 + 3]);
}

// ---------------- out[b] = dot(Y[b], X[b]) / (4*mag_b) ----------------
__global__ __launch_bounds__(256) void rowdot_kernel(const float* __restrict__ X,
                                                     const float* __restrict__ Y,
                                                     float* __restrict__ out)
{
    int b = blockIdx.x * 4 + (threadIdx.x >> 6);
    int lane = threadIdx.x & 63;
    const float4* xp = (const float4*)&X[(size_t)b * 512];
    const float4* yp = (const float4*)&Y[(size_t)b * 512];
    float dot = 0.0f, ss = 0.0f;
#pragma unroll
    for (int q = 0; q < 2; ++q) {
        float4 x = xp[lane + q * 64];
        float4 y = yp[lane + q * 64];
        dot += x.x * y.x + x.y * y.y + x.z * y.z + x.w * y.w;
        ss += x.x * x.x + x.y * x.y + x.z * x.z + x.w * x.w;
    }
#pragma unroll
    for (int off = 32; off; off >>= 1) {
        dot += __shfl_xor(dot, off, 64);
        ss += __shfl_xor(ss, off, 64);
    }
    if (lane == 0) out[b] = dot / (4.0f * (sqrtf(ss) + 1e-7f));
}

// ================= fallback fp32 path (round-1, known-good) =================
__global__ __launch_bounds__(256) void gemm_fp32(const float* __restrict__ A,
                                                 const float* __restrict__ B,
                                                 float* __restrict__ C,
                                                 int N, int K)
{
    __shared__ __align__(16) float sA[32][68];
    __shared__ __align__(16) float sB[32][68];
    int bm = blockIdx.x, bn = blockIdx.y;
    int tid = threadIdx.x;
    int tx = tid & 15, ty = tid >> 4;
    float acc[4][4] = {};
    for (int kt = 0; kt < K; kt += 32) {
#pragma unroll
        for (int i = 0; i < 2; ++i) {
            int lin = tid + i * 256;
            int r = lin >> 3;
            int c4 = lin & 7;
            float4 av = *reinterpret_cast<const float4*>(&A[(size_t)(bm * 64 + r) * K + kt + c4 * 4]);
            sA[c4 * 4 + 0][r] = av.x; sA[c4 * 4 + 1][r] = av.y;
            sA[c4 * 4 + 2][r] = av.z; sA[c4 * 4 + 3][r] = av.w;
        }
#pragma unroll
        for (int i = 0; i < 2; ++i) {
            int lin = tid + i * 256;
            int r = lin >> 4;
            int c4 = lin & 15;
            float4 bv = *reinterpret_cast<const float4*>(&B[(size_t)(kt + r) * N + bn * 64 + c4 * 4]);
            *reinterpret_cast<float4*>(&sB[r][c4 * 4]) = bv;
        }
        __syncthreads();
#pragma unroll
        for (int k = 0; k < 32; ++k) {
            float4 a = *reinterpret_cast<const float4*>(&sA[k][ty * 4]);
            float4 b = *reinterpret_cast<const float4*>(&sB[k][tx * 4]);
            acc[0][0] += a.x * b.x; acc[0][1] += a.x * b.y; acc[0][2] += a.x * b.z; acc[0][3] += a.x * b.w;
            acc[1][0] += a.y * b.x; acc[1][1] += a.y * b.y; acc[1][2] += a.y * b.z; acc[1][3] += a.y * b.w;
            acc[2][0] += a.z * b.x; acc[2][1] += a.z * b.y; acc[2][2] += a.z * b.z; acc[2][3] += a.z * b.w;
            acc[3][0] += a.w * b.x; acc[3][1] += a.w * b.y; acc[3][2] += a.w * b.z; acc[3][3] += a.w * b.w;
        }
        __syncthreads();
    }
#pragma unroll
    for (int i = 0; i < 4; ++i) {
        float4 v = make_float4(acc[i][0], acc[i][1], acc[i][2], acc[i][3]);
        *reinterpret_cast<float4*>(&C[(size_t)(bm * 64 + ty * 4 + i) * N + bn * 64 + tx * 4]) = v;
    }
}

__global__ __launch_bounds__(256) void ghat_kernel(const float* __restrict__ T,
                                                   float* __restrict__ G)
{
    __shared__ __align__(16) float sS[32][68];
    __shared__ __align__(16) float sT[32][68];
    int bs = blockIdx.x, bt = blockIdx.y;
    int tid = threadIdx.x;
    int tx = tid & 15, ty = tid >> 4;
    float acc[4][4] = {};
    for (int n0 = 0; n0 < 2048; n0 += 32) {
#pragma unroll
        for (int i = 0; i < 2; ++i) {
            int lin = tid + i * 256;
            int r = lin >> 4;
            int c4 = lin & 15;
            int n = n0 + r;
            float4 v1 = *reinterpret_cast<const float4*>(&T[(size_t)n * 512 + bs * 64 + c4 * 4]);
            *reinterpret_cast<float4*>(&sS[r][c4 * 4]) = v1;
            float4 v2 = *reinterpret_cast<const float4*>(&T[(size_t)n * 512 + bt * 64 + c4 * 4]);
            float p = 1.0f - 2.0f * (float)(__popc(n) & 1);
            v2.x *= p; v2.y *= p; v2.z *= p; v2.w *= p;
            *reinterpret_cast<float4*>(&sT[r][c4 * 4]) = v2;
        }
        __syncthreads();
#pragma unroll
        for (int k = 0; k < 32; ++k) {
            float4 a = *reinterpret_cast<const float4*>(&sS[k][ty * 4]);
            float4 b = *reinterpret_cast<const float4*>(&sT[k][tx * 4]);
            acc[0][0] += a.x * b.x; acc[0][1] += a.x * b.y; acc[0][2] += a.x * b.z; acc[0][3] += a.x * b.w;
            acc[1][0] += a.y * b.x; acc[1][1] += a.y * b.y; acc[1][2] += a.y * b.z; acc[1][3] += a.y * b.w;
            acc[2][0] += a.z * b.x; acc[2][1] += a.z * b.y; acc[2][2] += a.z * b.z; acc[2][3] += a.z * b.w;
            acc[3][0] += a.w * b.x; acc[3][1] += a.w * b.y; acc[3][2] += a.w * b.z; acc[3][3] += a.w * b.w;
        }
        __syncthreads();
    }
#pragma unroll
    for (int i = 0; i < 4; ++i) {
        float4 v = make_float4(acc[i][0], acc[i][1], acc[i][2], acc[i][3]);
        *reinterpret_cast<float4*>(&G[(size_t)(bs * 64 + ty * 4 + i) * 512 + bt * 64 + tx * 4]) = v;
    }
}

__global__ __launch_bounds__(256) void final_kernel(const float* __restrict__ X,
                                                    const float* __restrict__ G,
                                                    float* __restrict__ out)
{
    __shared__ __align__(16) float xs[8][512];
    __shared__ float mags[8];
    __shared__ float wsum[4][8];
    int b0 = blockIdx.x * 8;
    int tid = threadIdx.x;
#pragma unroll
    for (int i = 0; i < 4; ++i) {
        int lin = tid + i * 256;
        int r = lin >> 7;
        int c4 = lin & 127;
        float4 v = *reinterpret_cast<const float4*>(&X[(size_t)(b0 + r) * 512 + c4 * 4]);
        *reinterpret_cast<float4*>(&xs[r][c4 * 4]) = v;
    }
    __syncthreads();
    {
        int r = tid >> 5, ln = tid & 31;
        float ss = 0.0f;
        for (int j = ln; j < 512; j += 32) {
            float v = xs[r][j];
            ss += v * v;
        }
#pragma unroll
        for (int off = 16; off; off >>= 1) ss += __shfl_xor(ss, off, 64);
        if (ln == 0) mags[r] = sqrtf(ss) + 1e-7f;
    }
    __syncthreads();
    float xt0[8], xt1[8];
#pragma unroll
    for (int r = 0; r < 8; ++r) {
        xt0[r] = xs[r][tid];
        xt1[r] = xs[r][tid + 256];
    }
    float acc[8] = {};
    for (int s = 0; s < 512; ++s) {
        float g0 = G[(size_t)s * 512 + tid];
        float g1 = G[(size_t)s * 512 + tid + 256];
#pragma unroll
        for (int r = 0; r < 8; ++r) acc[r] += (g0 * xt0[r] + g1 * xt1[r]) * xs[r][s];
    }
#pragma unroll
    for (int r = 0; r < 8; ++r)
#pragma unroll
        for (int off = 32; off; off >>= 1) acc[r] += __shfl_xor(acc[r], off, 64);
    int wv = tid >> 6, ln = tid & 63;
    if (ln == 0)
#pragma unroll
        for (int r = 0; r < 8; ++r) wsum[wv][r] = acc[r];
    __syncthreads();
    if (tid < 8) {
        float s = wsum[0][tid] + wsum[1][tid] + wsum[2][tid] + wsum[3][tid];
        out[b0 + tid] = s / (4.0f * mags[tid]);
    }
}

// ================= launcher =================
extern "C" void kernel_launch(void* const* d_in, const int* in_sizes, int n_in,
                              void* d_out, int out_size, void* d_ws, size_t ws_size,
                              hipStream_t stream)
{
    const float* X = (const float*)d_in[0];
    const float* chang = (const float*)d_in[1];
    const float* kang = (const float*)d_in[2];
    const float* cent = (const float*)d_in[3];
    const float* kent = (const float*)d_in[4];
    float* out = (float*)d_out;

    // fast-path workspace layout (bytes)
    size_t off = 0;
    auto alloc = [&](size_t bytes) -> char* {
        char* p = (char*)d_ws + off;
        off += (bytes + 255) & ~(size_t)255;
        return p;
    };
    float* bufT = (float*)alloc(2048 * 512 * 4);
    float* TtA = (float*)alloc(512 * 2048 * 4);
    float* TtB = (float*)alloc(512 * 2048 * 4);
    float* Pa = (float*)alloc(2 * 1024 * 1024 * 4);
    float* Y = (float*)alloc(8192 * 512 * 4);
    float* C128 = (float*)alloc(2 * 128 * 128 * 4);
    float* K16 = (float*)alloc(2 * 16 * 16 * 4);
    unsigned short* Tthi = (unsigned short*)alloc(512 * 2048 * 2);
    unsigned short* Ttlo = (unsigned short*)alloc(512 * 2048 * 2);
    unsigned short* TtPhi = (unsigned short*)alloc(512 * 2048 * 2);
    unsigned short* TtPlo = (unsigned short*)alloc(512 * 2048 * 2);
    unsigned short* Ghi = (unsigned short*)alloc(512 * 512 * 2);
    unsigned short* Glo = (unsigned short*)alloc(512 * 512 * 2);
    unsigned short* Xhi = (unsigned short*)alloc(8192 * 512 * 2);
    unsigned short* Xlo = (unsigned short*)alloc(8192 * 512 * 2);
    unsigned short* ceHi = (unsigned short*)alloc(2048 * 2048 * 2);
    unsigned short* ceLo = (unsigned short*)alloc(2048 * 2048 * 2);
    unsigned short* keHi = (unsigned short*)alloc(2048 * 2048 * 2);
    unsigned short* keLo = (unsigned short*)alloc(2048 * 2048 * 2);
    bool fast = (off <= ws_size);

    if (fast) {
        build_rots_kernel<<<64, 256, 0, stream>>>(chang, kang, C128, K16);
        // prep conversions (pure convert via reduce kernel, nchunks=1)
        reduce_hl_kernel<<<4096, 256, 0, stream>>>(cent, 1, 0, nullptr, ceHi, ceLo, nullptr, nullptr, 0);
        reduce_hl_kernel<<<4096, 256, 0, stream>>>(kent, 1, 0, nullptr, keHi, keLo, nullptr, nullptr, 0);
        reduce_hl_kernel<<<4096, 256, 0, stream>>>(X, 1, 0, nullptr, Xhi, Xlo, nullptr, nullptr, 0);

        collapse_kernel<<<(2048 * 512) / 256, 256, 0, stream>>>(kent, bufT);   // T0 = k@E
        krot_kernel<<<1, 512, 0, stream>>>(K16 + 256, bufT);                   // kr1
        transpose_convert_kernel<<<dim3(32, 8), 256, 0, stream>>>(bufT, Tthi, Ttlo);

        // GEMM1: k_ent
        gemm_hl_kernel<1><<<dim3(32, 8, 2), 256, 0, stream>>>(keHi, keLo, 2048, Tthi, Ttlo, 2048, Pa, 2048, 512, 1024);
        reduce_hl_kernel<<<1024, 256, 0, stream>>>(Pa, 2, 1024 * 1024, nullptr, Tthi, Ttlo, nullptr, nullptr, 0);
        // GEMM2: c_ent -> fp32 only (chrot next)
        gemm_hl_kernel<1><<<dim3(32, 8, 2), 256, 0, stream>>>(ceHi, ceLo, 2048, Tthi, Ttlo, 2048, Pa, 2048, 512, 1024);
        reduce_hl_kernel<<<1024, 256, 0, stream>>>(Pa, 2, 1024 * 1024, TtA, nullptr, nullptr, nullptr, nullptr, 0);
        chrot_t_kernel<<<512, 256, 0, stream>>>(C128 + 16384, TtA, TtB);       // ch1
        krot_t_kernel<<<2, 256, 0, stream>>>(K16, TtB);                        // kr0
        reduce_hl_kernel<<<1024, 256, 0, stream>>>(TtB, 1, 0, nullptr, Tthi, Ttlo, nullptr, nullptr, 0);
        // GEMM3: k_ent
        gemm_hl_kernel<1><<<dim3(32, 8, 2), 256, 0, stream>>>(keHi, keLo, 2048, Tthi, Ttlo, 2048, Pa, 2048, 512, 1024);
        reduce_hl_kernel<<<1024, 256, 0, stream>>>(Pa, 2, 1024 * 1024, nullptr, Tthi, Ttlo, nullptr, nullptr, 0);
        // GEMM4: c_ent -> fp32 only (chrot next)
        gemm_hl_kernel<1><<<dim3(32, 8, 2), 256, 0, stream>>>(ceHi, ceLo, 2048, Tthi, Ttlo, 2048, Pa, 2048, 512, 1024);
        reduce_hl_kernel<<<1024, 256, 0, stream>>>(Pa, 2, 1024 * 1024, TtA, nullptr, nullptr, nullptr, nullptr, 0);
        chrot_t_kernel<<<512, 256, 0, stream>>>(C128, TtA, TtB);               // ch0
        reduce_hl_kernel<<<1024, 256, 0, stream>>>(TtB, 1, 0, nullptr, Tthi, Ttlo, nullptr, nullptr, 0);
        // GEMM5: c_ent -> hi/lo + parity copy
        gemm_hl_kernel<1><<<dim3(32, 8, 2), 256, 0, stream>>>(ceHi, ceLo, 2048, Tthi, Ttlo, 2048, Pa, 2048, 512, 1024);
        reduce_hl_kernel<<<1024, 256, 0, stream>>>(Pa, 2, 1024 * 1024, nullptr, Tthi, Ttlo, TtPhi, TtPlo, 2047);
        // ghat: G[t][s] = sum_n Tt7[s][n] * par(n) * Tt7[t][n]
        gemm_hl_kernel<1><<<dim3(8, 8, 8), 256, 0, stream>>>(Tthi, Ttlo, 2048, TtPhi, TtPlo, 2048, Pa, 512, 512, 256);
        reduce_hl_kernel<<<256, 256, 0, stream>>>(Pa, 8, 256 * 1024, nullptr, Ghi, Glo, nullptr, nullptr, 0);
        // final: Y[b][t] = sum_s X[b][s] * G[t][s]
        gemm_hl_kernel<0><<<dim3(128, 8, 1), 256, 0, stream>>>(Xhi, Xlo, 512, Ghi, Glo, 512, Y, 8192, 512, 512);
        rowdot_kernel<<<2048, 256, 0, stream>>>(X, Y, out);
    } else {
        // fp32 fallback (round-1 path)
        float* ws = (float*)d_ws;
        float* Ta = ws;
        float* Tb = Ta + 2048 * 512;
        float* G = Tb + 2048 * 512;
        float* C128f = G + 512 * 512;
        float* K16f = C128f + 2 * 128 * 128;

        build_rots_kernel<<<64, 256, 0, stream>>>(chang, kang, C128f, K16f);
        collapse_kernel<<<(2048 * 512) / 256, 256, 0, stream>>>(kent, Ta);
        krot_kernel<<<1, 512, 0, stream>>>(K16f + 256, Ta);
        gemm_fp32<<<dim3(32, 8), 256, 0, stream>>>(kent, Ta, Tb, 512, 2048);
        gemm_fp32<<<dim3(32, 8), 256, 0, stream>>>(cent, Tb, Ta, 512, 2048);
        gemm_fp32<<<dim3(2, 128), 256, 0, stream>>>(C128f + 16384, Ta, Tb, 8192, 128);
        krot_kernel<<<1, 512, 0, stream>>>(K16f, Tb);
        gemm_fp32<<<dim3(32, 8), 256, 0, stream>>>(kent, Tb, Ta, 512, 2048);
        gemm_fp32<<<dim3(32, 8), 256, 0, stream>>>(cent, Ta, Tb, 512, 2048);
        gemm_fp32<<<dim3(2, 128), 256, 0, stream>>>(C128f, Tb, Ta, 8192, 128);
        gemm_fp32<<<dim3(32, 8), 256, 0, stream>>>(cent, Ta, Tb, 512, 2048);
        ghat_kernel<<<dim3(8, 8), 256, 0, stream>>>(Tb, G);
        final_kernel<<<8192 / 8, 256, 0, stream>>>(X, G, out);
    }
}

// Round 3
// 242.332 us; speedup vs baseline: 2.9579x; 1.0101x over previous
//
#include <hip/hip_runtime.h>
#include <math.h>

#ifndef M_PI
#define M_PI 3.14159265358979323846
#endif

// out[b] = (x_b^T Ghat x_b) / (4 * mag_b),  mag = sqrt(sum x^2)+1e-7
// Ghat = (M E)^T diag(parity) (M E),  chain applied right-to-left to E,
// T kept transposed as Tt[512][2048]. Dense products: bf16 hi/lo split MFMA.

typedef __attribute__((ext_vector_type(8))) short bf16x8;
typedef __attribute__((ext_vector_type(16))) float f32x16;
typedef unsigned short ushort_t;

// ---------------- helpers ----------------
__device__ __forceinline__ unsigned short bf16_rne(float f) {
    unsigned u = __float_as_uint(f);
    unsigned r = u + 0x7FFFu + ((u >> 16) & 1u);
    return (unsigned short)(r >> 16);
}
__device__ __forceinline__ void split2(float f, unsigned short& h, unsigned short& l) {
    h = bf16_rne(f);
    float fh = __uint_as_float(((unsigned)h) << 16);
    l = bf16_rne(f - fh);
}
__device__ __forceinline__ void async_copy16(const void* gsrc, void* ldst) {
    __builtin_amdgcn_global_load_lds(
        (const __attribute__((address_space(1))) unsigned int*)gsrc,
        (__attribute__((address_space(3))) unsigned int*)ldst,
        16, 0, 0);
}

// ---------------- build rotation matrices ----------------
__global__ void build_rots_kernel(const float* __restrict__ ch_ang,
                                  const float* __restrict__ k_ang,
                                  float* __restrict__ C128,   // 2 x 128 x 128
                                  float* __restrict__ K16)    // 2 x 16 x 16
{
    int tid = blockIdx.x * blockDim.x + threadIdx.x;
    int stride = gridDim.x * blockDim.x;
    for (int idx = tid; idx < 2 * 128 * 128; idx += stride) {
        int l = idx >> 14;
        int rem = idx & 16383;
        int a = rem >> 7, b = rem & 127;
        float p = 1.0f;
#pragma unroll
        for (int q = 0; q < 7; ++q) {
            float half = ch_ang[l * 7 + q] * (float)M_PI;
            float c = cosf(half), s = sinf(half);
            int ia = (a >> (6 - q)) & 1;
            int ib = (b >> (6 - q)) & 1;
            float e = ia ? (ib ? c : s) : (ib ? -s : c);
            p *= e;
        }
        C128[idx] = p;
    }
    for (int idx = tid; idx < 2 * 16 * 16; idx += stride) {
        int l = idx >> 8;
        int rem = idx & 255;
        int a = rem >> 4, b = rem & 15;
        float p = 1.0f;
#pragma unroll
        for (int q = 0; q < 4; ++q) {
            float half = k_ang[l * 4 + q] * 0.5f;
            float c = cosf(half), s = sinf(half);
            int ia = (a >> (3 - q)) & 1;
            int ib = (b >> (3 - q)) & 1;
            float e = ia ? (ib ? c : s) : (ib ? -s : c);
            p *= e;
        }
        K16[idx] = p;
    }
}

// ---------------- convert cent+kent -> hi/lo in one launch ----------------
__global__ __launch_bounds__(256) void entprep_kernel(const float* __restrict__ cent,
                                                      const float* __restrict__ kent,
                                                      unsigned short* __restrict__ ceHi,
                                                      unsigned short* __restrict__ ceLo,
                                                      unsigned short* __restrict__ keHi,
                                                      unsigned short* __restrict__ keLo)
{
    int blk = blockIdx.x;
    const float* src = (blk < 4096) ? cent : kent;
    unsigned short* oh = (blk < 4096) ? ceHi : keHi;
    unsigned short* ol = (blk < 4096) ? ceLo : keLo;
    size_t base = (size_t)(blk & 4095) * 1024 + (size_t)threadIdx.x * 4;
    float4 v = *(const float4*)&src[base];
    float f[4] = {v.x, v.y, v.z, v.w};
    unsigned short h[4], l[4];
#pragma unroll
    for (int q = 0; q < 4; ++q) split2(f[q], h[q], l[q]);
    *(uint2*)&oh[base] = make_uint2((unsigned)h[0] | ((unsigned)h[1] << 16),
                                    (unsigned)h[2] | ((unsigned)h[3] << 16));
    *(uint2*)&ol[base] = make_uint2((unsigned)l[0] | ((unsigned)l[1] << 16),
                                    (unsigned)l[2] | ((unsigned)l[3] << 16));
}

// ---------------- X -> hi/lo + mag + zero acc (2 rows per block) ----------------
__global__ __launch_bounds__(256) void xprep_kernel(const float* __restrict__ X,
                                                    unsigned short* __restrict__ Xhi,
                                                    unsigned short* __restrict__ Xlo,
                                                    float* __restrict__ mag,
                                                    float* __restrict__ acc)
{
    __shared__ float part[4];
    int tid = threadIdx.x;
    int b0 = blockIdx.x * 2;
    int row = tid >> 7;            // 0/1
    int c4 = tid & 127;
    size_t base = (size_t)(b0 + row) * 512 + (size_t)c4 * 4;
    float4 v = *(const float4*)&X[base];
    float f[4] = {v.x, v.y, v.z, v.w};
    unsigned short h[4], l[4];
#pragma unroll
    for (int q = 0; q < 4; ++q) split2(f[q], h[q], l[q]);
    *(uint2*)&Xhi[base] = make_uint2((unsigned)h[0] | ((unsigned)h[1] << 16),
                                     (unsigned)h[2] | ((unsigned)h[3] << 16));
    *(uint2*)&Xlo[base] = make_uint2((unsigned)l[0] | ((unsigned)l[1] << 16),
                                     (unsigned)l[2] | ((unsigned)l[3] << 16));
    float ss = v.x * v.x + v.y * v.y + v.z * v.z + v.w * v.w;
#pragma unroll
    for (int off = 32; off; off >>= 1) ss += __shfl_xor(ss, off, 64);
    int w = tid >> 6, lane = tid & 63;
    if (lane == 0) part[w] = ss;
    __syncthreads();
    if (tid == 0) {
        mag[b0] = sqrtf(part[0] + part[1]) + 1e-7f;
        acc[b0] = 0.0f;
    }
    if (tid == 128) {
        mag[b0 + 1] = sqrtf(part[2] + part[3]) + 1e-7f;
        acc[b0 + 1] = 0.0f;
    }
}

// ---------------- T0 = k_ent @ E  (column collapse), T layout [2048][512] ----------------
__global__ __launch_bounds__(256) void collapse_kernel(const float* __restrict__ kent,
                                                       float* __restrict__ T)
{
    int idx = blockIdx.x * blockDim.x + threadIdx.x;
    if (idx >= 2048 * 512) return;
    int n = idx >> 9, s = idx & 511;
    const float* row = kent + (size_t)n * 2048;
    float acc = 0.0f;
#pragma unroll
    for (int dj = 0; dj < 2; ++dj) {
        int j = 2 * s + dj;
        int m0 = ((j >> 4) << 5) | (j & 15);
        acc += row[m0] + row[m0 + 16];
    }
    T[idx] = acc;
}

// ---------------- transpose T[2048][512] -> Tt hi/lo [512][2048], kr1 fused on last tile ----------------
__global__ __launch_bounds__(256) void transpose_convert_kernel(const float* __restrict__ T,
                                                                const float* __restrict__ K16l,
                                                                unsigned short* __restrict__ Hi,
                                                                unsigned short* __restrict__ Lo)
{
    __shared__ float tile[64][65];
    int n0 = blockIdx.x * 64, s0 = blockIdx.y * 64;
    int tid = threadIdx.x;
#pragma unroll
    for (int p = 0; p < 4; ++p) {
        int lin = tid + p * 256;
        int r = lin >> 4, c4 = lin & 15;
        float4 v = *(const float4*)&T[(size_t)(n0 + r) * 512 + s0 + c4 * 4];
        tile[r][c4 * 4 + 0] = v.x; tile[r][c4 * 4 + 1] = v.y;
        tile[r][c4 * 4 + 2] = v.z; tile[r][c4 * 4 + 3] = v.w;
    }
    __syncthreads();
    if (n0 == 1984) {   // global rows 2032..2047 = local 48..63: apply kr1
        float o[16];
        if (tid < 64) {
#pragma unroll
            for (int i = 0; i < 16; ++i) {
                float a = 0.0f;
#pragma unroll
                for (int j = 0; j < 16; ++j) a += K16l[i * 16 + j] * tile[48 + j][tid];
                o[i] = a;
            }
        }
        __syncthreads();
        if (tid < 64) {
#pragma unroll
            for (int i = 0; i < 16; ++i) tile[48 + i][tid] = o[i];
        }
        __syncthreads();
    }
#pragma unroll
    for (int p = 0; p < 4; ++p) {
        int lin = tid + p * 256;
        int sl = lin >> 4, j4 = lin & 15;
        unsigned short h[4], l[4];
#pragma unroll
        for (int q = 0; q < 4; ++q) split2(tile[j4 * 4 + q][sl], h[q], l[q]);
        size_t o = (size_t)(s0 + sl) * 2048 + n0 + j4 * 4;
        *(uint2*)&Hi[o] = make_uint2((unsigned)h[0] | ((unsigned)h[1] << 16),
                                     (unsigned)h[2] | ((unsigned)h[3] << 16));
        *(uint2*)&Lo[o] = make_uint2((unsigned)l[0] | ((unsigned)l[1] << 16),
                                     (unsigned)l[2] | ((unsigned)l[3] << 16));
    }
}

// ---------------- chrot (+optional krot) on Tt fp32 -> hi/lo bf16 ----------------
// out[s][16a+t] = sum_a' C[a][a'] in[s][16a'+t]; then optional K16 on cols 2032..2047
__global__ __launch_bounds__(256) void chrot_t_kernel(const float* __restrict__ C,
                                                      const float* __restrict__ K16l,  // may be null
                                                      const float* __restrict__ in,
                                                      unsigned short* __restrict__ outH,
                                                      unsigned short* __restrict__ outL)
{
    __shared__ float row[2048];
    __shared__ float orow[2048];
    int s = blockIdx.x;
    int tid = threadIdx.x;
    for (int i = tid; i < 512; i += 256) {
        float4 v = *(const float4*)&in[(size_t)s * 2048 + i * 4];
        *(float4*)&row[i * 4] = v;
    }
    __syncthreads();
    int a = tid >> 1, th = (tid & 1) * 8;
    float res[8];
#pragma unroll
    for (int j = 0; j < 8; ++j) res[j] = 0.0f;
    for (int ap = 0; ap < 128; ++ap) {
        float c = C[a * 128 + ap];
#pragma unroll
        for (int j = 0; j < 8; ++j) res[j] += c * row[ap * 16 + th + j];
    }
#pragma unroll
    for (int j = 0; j < 8; ++j) orow[a * 16 + th + j] = res[j];
    __syncthreads();
    if (K16l) {
        float o = 0.0f;
        if (tid < 16) {
#pragma unroll
            for (int j = 0; j < 16; ++j) o += K16l[tid * 16 + j] * orow[2032 + j];
        }
        __syncthreads();
        if (tid < 16) orow[2032 + tid] = o;
        __syncthreads();
    }
    // convert 8 elems per thread
    size_t base = (size_t)s * 2048 + (size_t)tid * 8;
    unsigned short h[8], l[8];
#pragma unroll
    for (int q = 0; q < 8; ++q) split2(orow[tid * 8 + q], h[q], l[q]);
    uint4 hv, lv;
    hv.x = (unsigned)h[0] | ((unsigned)h[1] << 16); hv.y = (unsigned)h[2] | ((unsigned)h[3] << 16);
    hv.z = (unsigned)h[4] | ((unsigned)h[5] << 16); hv.w = (unsigned)h[6] | ((unsigned)h[7] << 16);
    lv.x = (unsigned)l[0] | ((unsigned)l[1] << 16); lv.y = (unsigned)l[2] | ((unsigned)l[3] << 16);
    lv.z = (unsigned)l[4] | ((unsigned)l[5] << 16); lv.w = (unsigned)l[6] | ((unsigned)l[7] << 16);
    *(uint4*)&outH[base] = hv;
    *(uint4*)&outL[base] = lv;
}

// ---------------- reduce split-K partials -> hi/lo (ghat only) ----------------
__global__ __launch_bounds__(256) void reduce_hl_kernel(const float* __restrict__ P, int nchunks, int csize,
                                                        unsigned short* __restrict__ outH,
                                                        unsigned short* __restrict__ outL)
{
    int i4 = blockIdx.x * 256 + threadIdx.x;
    size_t base = (size_t)i4 * 4;
    float4 v = *(const float4*)&P[base];
    for (int c = 1; c < nchunks; ++c) {
        float4 u = *(const float4*)&P[(size_t)c * csize + base];
        v.x += u.x; v.y += u.y; v.z += u.z; v.w += u.w;
    }
    float f[4] = {v.x, v.y, v.z, v.w};
    unsigned short h[4], l[4];
#pragma unroll
    for (int q = 0; q < 4; ++q) split2(f[q], h[q], l[q]);
    *(uint2*)&outH[base] = make_uint2((unsigned)h[0] | ((unsigned)h[1] << 16),
                                      (unsigned)h[2] | ((unsigned)h[3] << 16));
    *(uint2*)&outL[base] = make_uint2((unsigned)l[0] | ((unsigned)l[1] << 16),
                                      (unsigned)l[2] | ((unsigned)l[3] << 16));
}

// ---------------- hi/lo split bf16 MFMA GEMM, double-buffered, fused epilogues ----------------
// Computes C[M,N] = A[M,K]@B^T[N,K]  (both operands row-major with k contiguous).
// 64x64 tile, 4 waves k-split over each 64-k step, LDS tree-reduce at end.
// EPI 0: write fp32 transposed Cout[(n)*M+m]
// EPI 1: write hi/lo bf16 transposed outH/outL[(n)*M+m]
// EPI 2: EPI1 + parity-flipped copies outPH/outPL
// EPI 3: EPI0 into Cout + kc*M*N (split-K partials, grid.z chunks)
// EPI 4: fused row-dot: atomicAdd(accOut[bm*64+row], sum_col Ytile*X)
template<int EPI>
__global__ __launch_bounds__(256) void gemm_hl_kernel(
    const unsigned short* __restrict__ Ahi, const unsigned short* __restrict__ Alo, int ldA,
    const unsigned short* __restrict__ Bhi, const unsigned short* __restrict__ Blo, int ldB,
    float* __restrict__ Cout,
    unsigned short* __restrict__ outH, unsigned short* __restrict__ outL,
    unsigned short* __restrict__ outPH, unsigned short* __restrict__ outPL,
    const float* __restrict__ Xf, float* __restrict__ accOut,
    int M, int N, int Kchunk)
{
    __shared__ __align__(16) char smem[65536];  // 2 buffers x (Ah|Al|Bh|Bl, 8KB each)
    const int tid = threadIdx.x;
    const int lane = tid & 63;
    const int w = tid >> 6;
    const int bm = blockIdx.x, bn = blockIdx.y, kc = blockIdx.z;
    const int kbase = kc * Kchunk;

    f32x16 acc[2][2];
#pragma unroll
    for (int i = 0; i < 2; ++i)
#pragma unroll
        for (int j = 0; j < 2; ++j)
#pragma unroll
            for (int q = 0; q < 16; ++q) acc[i][j][q] = 0.0f;

    const int col = lane & 31;
    const int hi = lane >> 5;
    const int k16 = w * 16;
    int aaddr[2];
#pragma unroll
    for (int ms = 0; ms < 2; ++ms) {
        int row = ms * 32 + col;
        int cb = (k16 + hi * 8) * 2;
        aaddr[ms] = row * 128 + (cb ^ ((row & 7) << 4));
    }
    int srow[2], sge[2], sdst[2];
#pragma unroll
    for (int p = 0; p < 2; ++p) {
        int slot = p * 4096 + tid * 16;
        int r = slot >> 7;
        int pc = slot & 127;
        int lc = pc ^ ((r & 7) << 4);
        srow[p] = r;
        sge[p] = lc >> 1;
        sdst[p] = p * 4096 + w * 1024;
    }

#define STAGE(BUF, KG)                                                                     \
    {                                                                                      \
        _Pragma("unroll")                                                                  \
        for (int p = 0; p < 2; ++p) {                                                      \
            int ge = (KG) + sge[p];                                                        \
            async_copy16(Ahi + (size_t)(bm * 64 + srow[p]) * ldA + ge,                     \
                         &smem[(BUF) * 32768 + 0 + sdst[p]]);                              \
            async_copy16(Alo + (size_t)(bm * 64 + srow[p]) * ldA + ge,                     \
                         &smem[(BUF) * 32768 + 8192 + sdst[p]]);                           \
            async_copy16(Bhi + (size_t)(bn * 64 + srow[p]) * ldB + ge,                     \
                         &smem[(BUF) * 32768 + 16384 + sdst[p]]);                          \
            async_copy16(Blo + (size_t)(bn * 64 + srow[p]) * ldB + ge,                     \
                         &smem[(BUF) * 32768 + 24576 + sdst[p]]);                          \
        }                                                                                  \
    }

    const int nsteps = Kchunk >> 6;
    STAGE(0, kbase);
    __syncthreads();
    int cur = 0;
    for (int kt = 0; kt < nsteps; ++kt) {
        if (kt + 1 < nsteps) STAGE(cur ^ 1, kbase + ((kt + 1) << 6));
        const char* base = &smem[cur * 32768];
        bf16x8 ah[2], al[2], bh[2], bl[2];
#pragma unroll
        for (int ms = 0; ms < 2; ++ms) {
            ah[ms] = *(const bf16x8*)(base + 0 + aaddr[ms]);
            al[ms] = *(const bf16x8*)(base + 8192 + aaddr[ms]);
        }
#pragma unroll
        for (int ns = 0; ns < 2; ++ns) {
            bh[ns] = *(const bf16x8*)(base + 16384 + aaddr[ns]);
            bl[ns] = *(const bf16x8*)(base + 24576 + aaddr[ns]);
        }
#pragma unroll
        for (int ms = 0; ms < 2; ++ms)
#pragma unroll
            for (int ns = 0; ns < 2; ++ns) {
                acc[ms][ns] = __builtin_amdgcn_mfma_f32_32x32x16_bf16(ah[ms], bh[ns], acc[ms][ns], 0, 0, 0);
                acc[ms][ns] = __builtin_amdgcn_mfma_f32_32x32x16_bf16(ah[ms], bl[ns], acc[ms][ns], 0, 0, 0);
                acc[ms][ns] = __builtin_amdgcn_mfma_f32_32x32x16_bf16(al[ms], bh[ns], acc[ms][ns], 0, 0, 0);
            }
        __syncthreads();
        cur ^= 1;
    }
#undef STAGE

    // cross-wave k-split tree reduction through LDS
    float* red = (float*)smem;
    if (w >= 2) {
        float* dst = red + (w - 2) * 4096;
#pragma unroll
        for (int ms = 0; ms < 2; ++ms)
#pragma unroll
            for (int ns = 0; ns < 2; ++ns)
#pragma unroll
                for (int r = 0; r < 16; ++r) {
                    int rowr = (r & 3) + 8 * (r >> 2) + 4 * hi;
                    dst[(ms * 32 + rowr) * 64 + ns * 32 + col] = acc[ms][ns][r];
                }
    }
    __syncthreads();
    if (w < 2) {
        float* src = red + w * 4096;
#pragma unroll
        for (int ms = 0; ms < 2; ++ms)
#pragma unroll
            for (int ns = 0; ns < 2; ++ns)
#pragma unroll
                for (int r = 0; r < 16; ++r) {
                    int rowr = (r & 3) + 8 * (r >> 2) + 4 * hi;
                    acc[ms][ns][r] += src[(ms * 32 + rowr) * 64 + ns * 32 + col];
                }
    }
    __syncthreads();
    if (w == 1) {
#pragma unroll
        for (int ms = 0; ms < 2; ++ms)
#pragma unroll
            for (int ns = 0; ns < 2; ++ns)
#pragma unroll
                for (int r = 0; r < 16; ++r) {
                    int rowr = (r & 3) + 8 * (r >> 2) + 4 * hi;
                    red[(ms * 32 + rowr) * 64 + ns * 32 + col] = acc[ms][ns][r];
                }
    }
    __syncthreads();
    if (w == 0) {
#pragma unroll
        for (int ms = 0; ms < 2; ++ms)
#pragma unroll
            for (int ns = 0; ns < 2; ++ns)
#pragma unroll
                for (int r = 0; r < 16; ++r) {
                    int rowr = (r & 3) + 8 * (r >> 2) + 4 * hi;
                    acc[ms][ns][r] += red[(ms * 32 + rowr) * 64 + ns * 32 + col];
                }
        if (EPI == 0 || EPI == 3) {
            float* dstC = Cout + (EPI == 3 ? (size_t)kc * M * N : (size_t)0);
#pragma unroll
            for (int ms = 0; ms < 2; ++ms)
#pragma unroll
                for (int ns = 0; ns < 2; ++ns)
#pragma unroll
                    for (int g = 0; g < 4; ++g) {
                        int rowt = ms * 32 + 8 * g + 4 * hi;
                        float4 v = make_float4(acc[ms][ns][4 * g + 0], acc[ms][ns][4 * g + 1],
                                               acc[ms][ns][4 * g + 2], acc[ms][ns][4 * g + 3]);
                        *(float4*)&dstC[(size_t)(bn * 64 + ns * 32 + col) * M + bm * 64 + rowt] = v;
                    }
        }
        if (EPI == 1 || EPI == 2) {
#pragma unroll
            for (int ms = 0; ms < 2; ++ms)
#pragma unroll
                for (int ns = 0; ns < 2; ++ns)
#pragma unroll
                    for (int g = 0; g < 4; ++g) {
                        int rowt = ms * 32 + 8 * g + 4 * hi;
                        size_t o = (size_t)(bn * 64 + ns * 32 + col) * M + bm * 64 + rowt;
                        unsigned short h[4], l[4];
#pragma unroll
                        for (int q = 0; q < 4; ++q) split2(acc[ms][ns][4 * g + q], h[q], l[q]);
                        *(uint2*)&outH[o] = make_uint2((unsigned)h[0] | ((unsigned)h[1] << 16),
                                                       (unsigned)h[2] | ((unsigned)h[3] << 16));
                        *(uint2*)&outL[o] = make_uint2((unsigned)l[0] | ((unsigned)l[1] << 16),
                                                       (unsigned)l[2] | ((unsigned)l[3] << 16));
                        if (EPI == 2) {
                            unsigned short ph[4], pl[4];
#pragma unroll
                            for (int q = 0; q < 4; ++q) {
                                int n = bm * 64 + rowt + q;
                                unsigned short flip = (unsigned short)(((unsigned)(__popc(n) & 1)) << 15);
                                ph[q] = h[q] ^ flip;
                                pl[q] = l[q] ^ flip;
                            }
                            *(uint2*)&outPH[o] = make_uint2((unsigned)ph[0] | ((unsigned)ph[1] << 16),
                                                            (unsigned)ph[2] | ((unsigned)ph[3] << 16));
                            *(uint2*)&outPL[o] = make_uint2((unsigned)pl[0] | ((unsigned)pl[1] << 16),
                                                            (unsigned)pl[2] | ((unsigned)pl[3] << 16));
                        }
                    }
        }
        if (EPI == 4) {
            // store final Y tile to LDS as red[row*64+col]
#pragma unroll
            for (int ms = 0; ms < 2; ++ms)
#pragma unroll
                for (int ns = 0; ns < 2; ++ns)
#pragma unroll
                    for (int r = 0; r < 16; ++r) {
                        int rowr = (r & 3) + 8 * (r >> 2) + 4 * hi;
                        red[(ms * 32 + rowr) * 64 + ns * 32 + col] = acc[ms][ns][r];
                    }
        }
    }
    if (EPI == 4) {
        __syncthreads();
        int row = tid >> 2, q = tid & 3;
        const float* xrow = Xf + (size_t)(bm * 64 + row) * 512 + bn * 64 + q * 16;
        const float* yr = &red[row * 64 + q * 16];
        float s = 0.0f;
#pragma unroll
        for (int j4 = 0; j4 < 4; ++j4) {
            float4 x = *(const float4*)&xrow[j4 * 4];
            s += x.x * yr[j4 * 4 + 0] + x.y * yr[j4 * 4 + 1] +
                 x.z * yr[j4 * 4 + 2] + x.w * yr[j4 * 4 + 3];
        }
        s += __shfl_xor(s, 1, 64);
        s += __shfl_xor(s, 2, 64);
        if (q == 0) atomicAdd(&accOut[bm * 64 + row], s);
    }
}

// ---------------- out[b] = acc[b] / (4*mag[b]) ----------------
__global__ __launch_bounds__(256) void divide_kernel(const float* __restrict__ acc,
                                                     const float* __restrict__ mag,
                                                     float* __restrict__ out)
{
    int b = blockIdx.x * 256 + threadIdx.x;
    out[b] = acc[b] / (4.0f * mag[b]);
}

// ================= launcher =================
extern "C" void kernel_launch(void* const* d_in, const int* in_sizes, int n_in,
                              void* d_out, int out_size, void* d_ws, size_t ws_size,
                              hipStream_t stream)
{
    const float* X = (const float*)d_in[0];
    const float* chang = (const float*)d_in[1];
    const float* kang = (const float*)d_in[2];
    const float* cent = (const float*)d_in[3];
    const float* kent = (const float*)d_in[4];
    float* out = (float*)d_out;

    size_t off = 0;
    auto alloc = [&](size_t bytes) -> char* {
        char* p = (char*)d_ws + off;
        off += (bytes + 255) & ~(size_t)255;
        return p;
    };
    float* bufT = (float*)alloc(2048 * 512 * 4);            // T0 fp32
    float* TtA = (float*)alloc(512 * 2048 * 4);             // fp32 pre-chrot
    float* Pa = (float*)alloc(8 * 512 * 512 * 4);           // ghat partials
    float* C128 = (float*)alloc(2 * 128 * 128 * 4);
    float* K16 = (float*)alloc(2 * 16 * 16 * 4);
    float* mag = (float*)alloc(8192 * 4);
    float* acc = (float*)alloc(8192 * 4);
    unsigned short* T0hi = (unsigned short*)alloc(512 * 2048 * 2);
    unsigned short* T0lo = (unsigned short*)alloc(512 * 2048 * 2);
    unsigned short* T1hi = (unsigned short*)alloc(512 * 2048 * 2);
    unsigned short* T1lo = (unsigned short*)alloc(512 * 2048 * 2);
    unsigned short* TPhi = (unsigned short*)alloc(512 * 2048 * 2);
    unsigned short* TPlo = (unsigned short*)alloc(512 * 2048 * 2);
    unsigned short* Ghi = (unsigned short*)alloc(512 * 512 * 2);
    unsigned short* Glo = (unsigned short*)alloc(512 * 512 * 2);
    unsigned short* Xhi = (unsigned short*)alloc(8192 * 512 * 2);
    unsigned short* Xlo = (unsigned short*)alloc(8192 * 512 * 2);
    unsigned short* ceHi = (unsigned short*)alloc(2048 * 2048 * 2);
    unsigned short* ceLo = (unsigned short*)alloc(2048 * 2048 * 2);
    unsigned short* keHi = (unsigned short*)alloc(2048 * 2048 * 2);
    unsigned short* keLo = (unsigned short*)alloc(2048 * 2048 * 2);
    (void)ws_size;

    build_rots_kernel<<<64, 256, 0, stream>>>(chang, kang, C128, K16);
    entprep_kernel<<<8192, 256, 0, stream>>>(cent, kent, ceHi, ceLo, keHi, keLo);
    xprep_kernel<<<4096, 256, 0, stream>>>(X, Xhi, Xlo, mag, acc);

    collapse_kernel<<<(2048 * 512) / 256, 256, 0, stream>>>(kent, bufT);            // T0 = k@E
    transpose_convert_kernel<<<dim3(32, 8), 256, 0, stream>>>(bufT, K16 + 256, T0hi, T0lo); // +kr1

    // G1: kent @ T -> hi/lo (pair1)
    gemm_hl_kernel<1><<<dim3(32, 8, 1), 256, 0, stream>>>(
        keHi, keLo, 2048, T0hi, T0lo, 2048, nullptr, T1hi, T1lo, nullptr, nullptr,
        nullptr, nullptr, 2048, 512, 2048);
    // G2: cent @ T -> fp32 TtA
    gemm_hl_kernel<0><<<dim3(32, 8, 1), 256, 0, stream>>>(
        ceHi, ceLo, 2048, T1hi, T1lo, 2048, TtA, nullptr, nullptr, nullptr, nullptr,
        nullptr, nullptr, 2048, 512, 2048);
    // ch1 + kr0 -> hi/lo (pair0)
    chrot_t_kernel<<<512, 256, 0, stream>>>(C128 + 16384, K16, TtA, T0hi, T0lo);
    // G3: kent @ T -> hi/lo (pair1)
    gemm_hl_kernel<1><<<dim3(32, 8, 1), 256, 0, stream>>>(
        keHi, keLo, 2048, T0hi, T0lo, 2048, nullptr, T1hi, T1lo, nullptr, nullptr,
        nullptr, nullptr, 2048, 512, 2048);
    // G4: cent @ T -> fp32 TtA
    gemm_hl_kernel<0><<<dim3(32, 8, 1), 256, 0, stream>>>(
        ceHi, ceLo, 2048, T1hi, T1lo, 2048, TtA, nullptr, nullptr, nullptr, nullptr,
        nullptr, nullptr, 2048, 512, 2048);
    // ch0 -> hi/lo (pair0)
    chrot_t_kernel<<<512, 256, 0, stream>>>(C128, nullptr, TtA, T0hi, T0lo);
    // G5: cent @ T -> hi/lo (pair1) + parity copy
    gemm_hl_kernel<2><<<dim3(32, 8, 1), 256, 0, stream>>>(
        ceHi, ceLo, 2048, T0hi, T0lo, 2048, nullptr, T1hi, T1lo, TPhi, TPlo,
        nullptr, nullptr, 2048, 512, 2048);
    // ghat: split-K=8 partials then reduce -> Ghi/Glo
    gemm_hl_kernel<3><<<dim3(8, 8, 8), 256, 0, stream>>>(
        T1hi, T1lo, 2048, TPhi, TPlo, 2048, Pa, nullptr, nullptr, nullptr, nullptr,
        nullptr, nullptr, 512, 512, 256);
    reduce_hl_kernel<<<256, 256, 0, stream>>>(Pa, 8, 512 * 512, Ghi, Glo);
    // final: fused X@G^T row-dot -> acc
    gemm_hl_kernel<4><<<dim3(128, 8, 1), 256, 0, stream>>>(
        Xhi, Xlo, 512, Ghi, Glo, 512, nullptr, nullptr, nullptr, nullptr, nullptr,
        X, acc, 8192, 512, 512);
    divide_kernel<<<32, 256, 0, stream>>>(acc, mag, out);
}

// Round 4
// 221.258 us; speedup vs baseline: 3.2396x; 1.0952x over previous
//
#include <hip/hip_runtime.h>
#include <math.h>

#ifndef M_PI
#define M_PI 3.14159265358979323846
#endif

// out[b] = (x_b^T Ghat x_b) / (4 * mag_b),  mag = sqrt(sum x^2)+1e-7
// Ghat = (M E)^T diag(parity) (M E),  chain applied right-to-left to E,
// T kept transposed as Tt[512][2048]. Dense products: bf16 hi/lo split MFMA.

typedef __attribute__((ext_vector_type(8))) short bf16x8;
typedef __attribute__((ext_vector_type(16))) float f32x16;

// ---------------- helpers ----------------
__device__ __forceinline__ unsigned short bf16_rne(float f) {
    unsigned u = __float_as_uint(f);
    unsigned r = u + 0x7FFFu + ((u >> 16) & 1u);
    return (unsigned short)(r >> 16);
}
__device__ __forceinline__ void split2(float f, unsigned short& h, unsigned short& l) {
    h = bf16_rne(f);
    float fh = __uint_as_float(((unsigned)h) << 16);
    l = bf16_rne(f - fh);
}
__device__ __forceinline__ void async_copy16(const void* gsrc, void* ldst) {
    __builtin_amdgcn_global_load_lds(
        (const __attribute__((address_space(1))) unsigned int*)gsrc,
        (__attribute__((address_space(3))) unsigned int*)ldst,
        16, 0, 0);
}

// ---------------- merged prep: rots + ent convert + X convert + collapse ----------------
__global__ __launch_bounds__(256) void prep_kernel(
    const float* __restrict__ X,
    const float* __restrict__ ch_ang, const float* __restrict__ k_ang,
    const float* __restrict__ cent, const float* __restrict__ kent,
    unsigned short* __restrict__ ceHi, unsigned short* __restrict__ ceLo,
    unsigned short* __restrict__ keHi, unsigned short* __restrict__ keLo,
    unsigned short* __restrict__ Xhi, unsigned short* __restrict__ Xlo,
    float* __restrict__ mag, float* __restrict__ acc,
    float* __restrict__ bufT,
    float* __restrict__ C128, float* __restrict__ K16)
{
    __shared__ float part[4];
    int blk = blockIdx.x;
    int tid = threadIdx.x;

    if (blk < 8192) {
        // ---- ent convert (cent: 0..4095, kent: 4096..8191)
        const float* src = (blk < 4096) ? cent : kent;
        unsigned short* oh = (blk < 4096) ? ceHi : keHi;
        unsigned short* ol = (blk < 4096) ? ceLo : keLo;
        size_t base = (size_t)(blk & 4095) * 1024 + (size_t)tid * 4;
        float4 v = *(const float4*)&src[base];
        float f[4] = {v.x, v.y, v.z, v.w};
        unsigned short h[4], l[4];
#pragma unroll
        for (int q = 0; q < 4; ++q) split2(f[q], h[q], l[q]);
        *(uint2*)&oh[base] = make_uint2((unsigned)h[0] | ((unsigned)h[1] << 16),
                                        (unsigned)h[2] | ((unsigned)h[3] << 16));
        *(uint2*)&ol[base] = make_uint2((unsigned)l[0] | ((unsigned)l[1] << 16),
                                        (unsigned)l[2] | ((unsigned)l[3] << 16));
    } else if (blk < 12288) {
        // ---- X convert + mag + zero acc (2 rows per block)
        int b0 = (blk - 8192) * 2;
        int row = tid >> 7;
        int c4 = tid & 127;
        size_t base = (size_t)(b0 + row) * 512 + (size_t)c4 * 4;
        float4 v = *(const float4*)&X[base];
        float f[4] = {v.x, v.y, v.z, v.w};
        unsigned short h[4], l[4];
#pragma unroll
        for (int q = 0; q < 4; ++q) split2(f[q], h[q], l[q]);
        *(uint2*)&Xhi[base] = make_uint2((unsigned)h[0] | ((unsigned)h[1] << 16),
                                         (unsigned)h[2] | ((unsigned)h[3] << 16));
        *(uint2*)&Xlo[base] = make_uint2((unsigned)l[0] | ((unsigned)l[1] << 16),
                                         (unsigned)l[2] | ((unsigned)l[3] << 16));
        float ss = v.x * v.x + v.y * v.y + v.z * v.z + v.w * v.w;
#pragma unroll
        for (int off = 32; off; off >>= 1) ss += __shfl_xor(ss, off, 64);
        int w = tid >> 6, lane = tid & 63;
        if (lane == 0) part[w] = ss;
        __syncthreads();
        if (tid == 0) {
            mag[b0] = sqrtf(part[0] + part[1]) + 1e-7f;
            acc[b0] = 0.0f;
        }
        if (tid == 128) {
            mag[b0 + 1] = sqrtf(part[2] + part[3]) + 1e-7f;
            acc[b0 + 1] = 0.0f;
        }
    } else if (blk < 16384) {
        // ---- collapse: T0 = k_ent @ E, layout [2048][512]
        int idx = (blk - 12288) * 256 + tid;
        int n = idx >> 9, s = idx & 511;
        const float* row = kent + (size_t)n * 2048;
        float a = 0.0f;
#pragma unroll
        for (int dj = 0; dj < 2; ++dj) {
            int j = 2 * s + dj;
            int m0 = ((j >> 4) << 5) | (j & 15);
            a += row[m0] + row[m0 + 16];
        }
        bufT[idx] = a;
    } else {
        // ---- rotation matrices (64 blocks, grid-stride as 16384 threads)
        int t = (blk - 16384) * 256 + tid;
        int stride = 64 * 256;
        for (int idx = t; idx < 2 * 128 * 128; idx += stride) {
            int l = idx >> 14;
            int rem = idx & 16383;
            int a = rem >> 7, b = rem & 127;
            float p = 1.0f;
#pragma unroll
            for (int q = 0; q < 7; ++q) {
                float half = ch_ang[l * 7 + q] * (float)M_PI;
                float c = cosf(half), s = sinf(half);
                int ia = (a >> (6 - q)) & 1;
                int ib = (b >> (6 - q)) & 1;
                float e = ia ? (ib ? c : s) : (ib ? -s : c);
                p *= e;
            }
            C128[idx] = p;
        }
        for (int idx = t; idx < 2 * 16 * 16; idx += stride) {
            int l = idx >> 8;
            int rem = idx & 255;
            int a = rem >> 4, b = rem & 15;
            float p = 1.0f;
#pragma unroll
            for (int q = 0; q < 4; ++q) {
                float half = k_ang[l * 4 + q] * 0.5f;
                float c = cosf(half), s = sinf(half);
                int ia = (a >> (3 - q)) & 1;
                int ib = (b >> (3 - q)) & 1;
                float e = ia ? (ib ? c : s) : (ib ? -s : c);
                p *= e;
            }
            K16[idx] = p;
        }
    }
}

// ---------------- transpose T[2048][512] -> Tt hi/lo [512][2048], kr1 fused on last tile ----------------
__global__ __launch_bounds__(256) void transpose_convert_kernel(const float* __restrict__ T,
                                                                const float* __restrict__ K16l,
                                                                unsigned short* __restrict__ Hi,
                                                                unsigned short* __restrict__ Lo)
{
    __shared__ float tile[64][65];
    int n0 = blockIdx.x * 64, s0 = blockIdx.y * 64;
    int tid = threadIdx.x;
#pragma unroll
    for (int p = 0; p < 4; ++p) {
        int lin = tid + p * 256;
        int r = lin >> 4, c4 = lin & 15;
        float4 v = *(const float4*)&T[(size_t)(n0 + r) * 512 + s0 + c4 * 4];
        tile[r][c4 * 4 + 0] = v.x; tile[r][c4 * 4 + 1] = v.y;
        tile[r][c4 * 4 + 2] = v.z; tile[r][c4 * 4 + 3] = v.w;
    }
    __syncthreads();
    if (n0 == 1984) {   // global rows 2032..2047 = local 48..63: apply kr1
        float o[16];
        if (tid < 64) {
#pragma unroll
            for (int i = 0; i < 16; ++i) {
                float a = 0.0f;
#pragma unroll
                for (int j = 0; j < 16; ++j) a += K16l[i * 16 + j] * tile[48 + j][tid];
                o[i] = a;
            }
        }
        __syncthreads();
        if (tid < 64) {
#pragma unroll
            for (int i = 0; i < 16; ++i) tile[48 + i][tid] = o[i];
        }
        __syncthreads();
    }
#pragma unroll
    for (int p = 0; p < 4; ++p) {
        int lin = tid + p * 256;
        int sl = lin >> 4, j4 = lin & 15;
        unsigned short h[4], l[4];
#pragma unroll
        for (int q = 0; q < 4; ++q) split2(tile[j4 * 4 + q][sl], h[q], l[q]);
        size_t o = (size_t)(s0 + sl) * 2048 + n0 + j4 * 4;
        *(uint2*)&Hi[o] = make_uint2((unsigned)h[0] | ((unsigned)h[1] << 16),
                                     (unsigned)h[2] | ((unsigned)h[3] << 16));
        *(uint2*)&Lo[o] = make_uint2((unsigned)l[0] | ((unsigned)l[1] << 16),
                                     (unsigned)l[2] | ((unsigned)l[3] << 16));
    }
}

// ---------------- chrot (+optional krot) on Tt fp32 -> hi/lo bf16 ----------------
__global__ __launch_bounds__(256) void chrot_t_kernel(const float* __restrict__ C,
                                                      const float* __restrict__ K16l,  // may be null
                                                      const float* __restrict__ in,
                                                      unsigned short* __restrict__ outH,
                                                      unsigned short* __restrict__ outL)
{
    __shared__ float row[2048];
    __shared__ float orow[2048];
    int s = blockIdx.x;
    int tid = threadIdx.x;
    for (int i = tid; i < 512; i += 256) {
        float4 v = *(const float4*)&in[(size_t)s * 2048 + i * 4];
        *(float4*)&row[i * 4] = v;
    }
    __syncthreads();
    int a = tid >> 1, th = (tid & 1) * 8;
    float res[8];
#pragma unroll
    for (int j = 0; j < 8; ++j) res[j] = 0.0f;
    for (int ap = 0; ap < 128; ++ap) {
        float c = C[a * 128 + ap];
#pragma unroll
        for (int j = 0; j < 8; ++j) res[j] += c * row[ap * 16 + th + j];
    }
#pragma unroll
    for (int j = 0; j < 8; ++j) orow[a * 16 + th + j] = res[j];
    __syncthreads();
    if (K16l) {
        float o = 0.0f;
        if (tid < 16) {
#pragma unroll
            for (int j = 0; j < 16; ++j) o += K16l[tid * 16 + j] * orow[2032 + j];
        }
        __syncthreads();
        if (tid < 16) orow[2032 + tid] = o;
        __syncthreads();
    }
    size_t base = (size_t)s * 2048 + (size_t)tid * 8;
    unsigned short h[8], l[8];
#pragma unroll
    for (int q = 0; q < 8; ++q) split2(orow[tid * 8 + q], h[q], l[q]);
    uint4 hv, lv;
    hv.x = (unsigned)h[0] | ((unsigned)h[1] << 16); hv.y = (unsigned)h[2] | ((unsigned)h[3] << 16);
    hv.z = (unsigned)h[4] | ((unsigned)h[5] << 16); hv.w = (unsigned)h[6] | ((unsigned)h[7] << 16);
    lv.x = (unsigned)l[0] | ((unsigned)l[1] << 16); lv.y = (unsigned)l[2] | ((unsigned)l[3] << 16);
    lv.z = (unsigned)l[4] | ((unsigned)l[5] << 16); lv.w = (unsigned)l[6] | ((unsigned)l[7] << 16);
    *(uint4*)&outH[base] = hv;
    *(uint4*)&outL[base] = lv;
}

// ---------------- reduce split-K partials -> hi/lo (ghat only) ----------------
__global__ __launch_bounds__(256) void reduce_hl_kernel(const float* __restrict__ P, int nchunks, int csize,
                                                        unsigned short* __restrict__ outH,
                                                        unsigned short* __restrict__ outL)
{
    int i4 = blockIdx.x * 256 + threadIdx.x;
    size_t base = (size_t)i4 * 4;
    float4 v = *(const float4*)&P[base];
    for (int c = 1; c < nchunks; ++c) {
        float4 u = *(const float4*)&P[(size_t)c * csize + base];
        v.x += u.x; v.y += u.y; v.z += u.z; v.w += u.w;
    }
    float f[4] = {v.x, v.y, v.z, v.w};
    unsigned short h[4], l[4];
#pragma unroll
    for (int q = 0; q < 4; ++q) split2(f[q], h[q], l[q]);
    *(uint2*)&outH[base] = make_uint2((unsigned)h[0] | ((unsigned)h[1] << 16),
                                      (unsigned)h[2] | ((unsigned)h[3] << 16));
    *(uint2*)&outL[base] = make_uint2((unsigned)l[0] | ((unsigned)l[1] << 16),
                                      (unsigned)l[2] | ((unsigned)l[3] << 16));
}

// ---------------- hi/lo split bf16 MFMA GEMM, pipelined (counted vmcnt, raw barrier) ----------------
// C[M,N] = A[M,K]@B^T[N,K]; 64x64 tile, 4 waves k-split, LDS tree-reduce.
// EPI 0: fp32 transposed Cout[n*M+m]
// EPI 1: hi/lo bf16 transposed
// EPI 2: EPI1 + parity-flipped copies
// EPI 3: fp32 transposed into Cout + kc*M*N (split-K partials)
// EPI 4: fused row-dot: atomicAdd(accOut[bm*64+row], sum_col Ytile*X)
template<int EPI>
__global__ __launch_bounds__(256) void gemm_hl_kernel(
    const unsigned short* __restrict__ Ahi, const unsigned short* __restrict__ Alo, int ldA,
    const unsigned short* __restrict__ Bhi, const unsigned short* __restrict__ Blo, int ldB,
    float* __restrict__ Cout,
    unsigned short* __restrict__ outH, unsigned short* __restrict__ outL,
    unsigned short* __restrict__ outPH, unsigned short* __restrict__ outPL,
    const float* __restrict__ Xf, float* __restrict__ accOut,
    int M, int N, int Kchunk)
{
    __shared__ __align__(16) char smem[65536];  // 2 buffers x (Ah|Al|Bh|Bl, 8KB each)
    const int tid = threadIdx.x;
    const int lane = tid & 63;
    const int w = tid >> 6;
    const int bm = blockIdx.x, bn = blockIdx.y, kc = blockIdx.z;
    const int kbase = kc * Kchunk;

    f32x16 acc[2][2];
#pragma unroll
    for (int i = 0; i < 2; ++i)
#pragma unroll
        for (int j = 0; j < 2; ++j)
#pragma unroll
            for (int q = 0; q < 16; ++q) acc[i][j][q] = 0.0f;

    const int col = lane & 31;
    const int hi = lane >> 5;
    const int k16 = w * 16;
    int aaddr[2];
#pragma unroll
    for (int ms = 0; ms < 2; ++ms) {
        int row = ms * 32 + col;
        int cb = (k16 + hi * 8) * 2;
        aaddr[ms] = row * 128 + (cb ^ ((row & 7) << 4));
    }
    int srow[2], sge[2], sdst[2];
#pragma unroll
    for (int p = 0; p < 2; ++p) {
        int slot = p * 4096 + tid * 16;
        int r = slot >> 7;
        int pc = slot & 127;
        int lc = pc ^ ((r & 7) << 4);
        srow[p] = r;
        sge[p] = lc >> 1;
        sdst[p] = p * 4096 + w * 1024;
    }

#define STAGE(BUF, KG)                                                                     \
    {                                                                                      \
        _Pragma("unroll")                                                                  \
        for (int p = 0; p < 2; ++p) {                                                      \
            int ge = (KG) + sge[p];                                                        \
            async_copy16(Ahi + (size_t)(bm * 64 + srow[p]) * ldA + ge,                     \
                         &smem[(BUF) * 32768 + 0 + sdst[p]]);                              \
            async_copy16(Alo + (size_t)(bm * 64 + srow[p]) * ldA + ge,                     \
                         &smem[(BUF) * 32768 + 8192 + sdst[p]]);                           \
            async_copy16(Bhi + (size_t)(bn * 64 + srow[p]) * ldB + ge,                     \
                         &smem[(BUF) * 32768 + 16384 + sdst[p]]);                          \
            async_copy16(Blo + (size_t)(bn * 64 + srow[p]) * ldB + ge,                     \
                         &smem[(BUF) * 32768 + 24576 + sdst[p]]);                          \
        }                                                                                  \
    }

    const int nsteps = Kchunk >> 6;
    // prologue: stage tile 0, wait, barrier
    STAGE(0, kbase);
    asm volatile("s_waitcnt vmcnt(0)" ::: "memory");
    __builtin_amdgcn_s_barrier();
    __builtin_amdgcn_sched_barrier(0);

    int cur = 0;
    for (int kt = 0; kt < nsteps; ++kt) {
        const bool havenext = (kt + 1 < nsteps);
        if (havenext) STAGE(cur ^ 1, kbase + ((kt + 1) << 6));   // prefetch flies during compute
        __builtin_amdgcn_sched_barrier(0);
        const char* base = &smem[cur * 32768];
        bf16x8 ah[2], al[2], bh[2], bl[2];
#pragma unroll
        for (int ms = 0; ms < 2; ++ms) {
            ah[ms] = *(const bf16x8*)(base + 0 + aaddr[ms]);
            al[ms] = *(const bf16x8*)(base + 8192 + aaddr[ms]);
        }
#pragma unroll
        for (int ns = 0; ns < 2; ++ns) {
            bh[ns] = *(const bf16x8*)(base + 16384 + aaddr[ns]);
            bl[ns] = *(const bf16x8*)(base + 24576 + aaddr[ns]);
        }
#pragma unroll
        for (int ms = 0; ms < 2; ++ms)
#pragma unroll
            for (int ns = 0; ns < 2; ++ns) {
                acc[ms][ns] = __builtin_amdgcn_mfma_f32_32x32x16_bf16(ah[ms], bh[ns], acc[ms][ns], 0, 0, 0);
                acc[ms][ns] = __builtin_amdgcn_mfma_f32_32x32x16_bf16(ah[ms], bl[ns], acc[ms][ns], 0, 0, 0);
                acc[ms][ns] = __builtin_amdgcn_mfma_f32_32x32x16_bf16(al[ms], bh[ns], acc[ms][ns], 0, 0, 0);
            }
        __builtin_amdgcn_sched_barrier(0);
        if (havenext) {
            asm volatile("s_waitcnt vmcnt(0)" ::: "memory");     // own prefetch landed (flew over compute)
        }
        __builtin_amdgcn_s_barrier();                            // everyone done reading cur + next tile ready
        __builtin_amdgcn_sched_barrier(0);
        cur ^= 1;
    }
#undef STAGE

    // cross-wave k-split tree reduction through LDS
    float* red = (float*)smem;
    if (w >= 2) {
        float* dst = red + (w - 2) * 4096;
#pragma unroll
        for (int ms = 0; ms < 2; ++ms)
#pragma unroll
            for (int ns = 0; ns < 2; ++ns)
#pragma unroll
                for (int r = 0; r < 16; ++r) {
                    int rowr = (r & 3) + 8 * (r >> 2) + 4 * hi;
                    dst[(ms * 32 + rowr) * 64 + ns * 32 + col] = acc[ms][ns][r];
                }
    }
    __syncthreads();
    if (w < 2) {
        float* src = red + w * 4096;
#pragma unroll
        for (int ms = 0; ms < 2; ++ms)
#pragma unroll
            for (int ns = 0; ns < 2; ++ns)
#pragma unroll
                for (int r = 0; r < 16; ++r) {
                    int rowr = (r & 3) + 8 * (r >> 2) + 4 * hi;
                    acc[ms][ns][r] += src[(ms * 32 + rowr) * 64 + ns * 32 + col];
                }
    }
    __syncthreads();
    if (w == 1) {
#pragma unroll
        for (int ms = 0; ms < 2; ++ms)
#pragma unroll
            for (int ns = 0; ns < 2; ++ns)
#pragma unroll
                for (int r = 0; r < 16; ++r) {
                    int rowr = (r & 3) + 8 * (r >> 2) + 4 * hi;
                    red[(ms * 32 + rowr) * 64 + ns * 32 + col] = acc[ms][ns][r];
                }
    }
    __syncthreads();
    if (w == 0) {
#pragma unroll
        for (int ms = 0; ms < 2; ++ms)
#pragma unroll
            for (int ns = 0; ns < 2; ++ns)
#pragma unroll
                for (int r = 0; r < 16; ++r) {
                    int rowr = (r & 3) + 8 * (r >> 2) + 4 * hi;
                    acc[ms][ns][r] += red[(ms * 32 + rowr) * 64 + ns * 32 + col];
                }
        if (EPI == 0 || EPI == 3) {
            float* dstC = Cout + (EPI == 3 ? (size_t)kc * M * N : (size_t)0);
#pragma unroll
            for (int ms = 0; ms < 2; ++ms)
#pragma unroll
                for (int ns = 0; ns < 2; ++ns)
#pragma unroll
                    for (int g = 0; g < 4; ++g) {
                        int rowt = ms * 32 + 8 * g + 4 * hi;
                        float4 v = make_float4(acc[ms][ns][4 * g + 0], acc[ms][ns][4 * g + 1],
                                               acc[ms][ns][4 * g + 2], acc[ms][ns][4 * g + 3]);
                        *(float4*)&dstC[(size_t)(bn * 64 + ns * 32 + col) * M + bm * 64 + rowt] = v;
                    }
        }
        if (EPI == 1 || EPI == 2) {
#pragma unroll
            for (int ms = 0; ms < 2; ++ms)
#pragma unroll
                for (int ns = 0; ns < 2; ++ns)
#pragma unroll
                    for (int g = 0; g < 4; ++g) {
                        int rowt = ms * 32 + 8 * g + 4 * hi;
                        size_t o = (size_t)(bn * 64 + ns * 32 + col) * M + bm * 64 + rowt;
                        unsigned short h[4], l[4];
#pragma unroll
                        for (int q = 0; q < 4; ++q) split2(acc[ms][ns][4 * g + q], h[q], l[q]);
                        *(uint2*)&outH[o] = make_uint2((unsigned)h[0] | ((unsigned)h[1] << 16),
                                                       (unsigned)h[2] | ((unsigned)h[3] << 16));
                        *(uint2*)&outL[o] = make_uint2((unsigned)l[0] | ((unsigned)l[1] << 16),
                                                       (unsigned)l[2] | ((unsigned)l[3] << 16));
                        if (EPI == 2) {
                            unsigned short ph[4], pl[4];
#pragma unroll
                            for (int q = 0; q < 4; ++q) {
                                int n = bm * 64 + rowt + q;
                                unsigned short flip = (unsigned short)(((unsigned)(__popc(n) & 1)) << 15);
                                ph[q] = h[q] ^ flip;
                                pl[q] = l[q] ^ flip;
                            }
                            *(uint2*)&outPH[o] = make_uint2((unsigned)ph[0] | ((unsigned)ph[1] << 16),
                                                            (unsigned)ph[2] | ((unsigned)ph[3] << 16));
                            *(uint2*)&outPL[o] = make_uint2((unsigned)pl[0] | ((unsigned)pl[1] << 16),
                                                            (unsigned)pl[2] | ((unsigned)pl[3] << 16));
                        }
                    }
        }
        if (EPI == 4) {
#pragma unroll
            for (int ms = 0; ms < 2; ++ms)
#pragma unroll
                for (int ns = 0; ns < 2; ++ns)
#pragma unroll
                    for (int r = 0; r < 16; ++r) {
                        int rowr = (r & 3) + 8 * (r >> 2) + 4 * hi;
                        red[(ms * 32 + rowr) * 64 + ns * 32 + col] = acc[ms][ns][r];
                    }
        }
    }
    if (EPI == 4) {
        __syncthreads();
        int row = tid >> 2, q = tid & 3;
        const float* xrow = Xf + (size_t)(bm * 64 + row) * 512 + bn * 64 + q * 16;
        const float* yr = &red[row * 64 + q * 16];
        float s = 0.0f;
#pragma unroll
        for (int j4 = 0; j4 < 4; ++j4) {
            float4 x = *(const float4*)&xrow[j4 * 4];
            s += x.x * yr[j4 * 4 + 0] + x.y * yr[j4 * 4 + 1] +
                 x.z * yr[j4 * 4 + 2] + x.w * yr[j4 * 4 + 3];
        }
        s += __shfl_xor(s, 1, 64);
        s += __shfl_xor(s, 2, 64);
        if (q == 0) atomicAdd(&accOut[bm * 64 + row], s);
    }
}

// ---------------- out[b] = acc[b] / (4*mag[b]) ----------------
__global__ __launch_bounds__(256) void divide_kernel(const float* __restrict__ acc,
                                                     const float* __restrict__ mag,
                                                     float* __restrict__ out)
{
    int b = blockIdx.x * 256 + threadIdx.x;
    out[b] = acc[b] / (4.0f * mag[b]);
}

// ================= launcher =================
extern "C" void kernel_launch(void* const* d_in, const int* in_sizes, int n_in,
                              void* d_out, int out_size, void* d_ws, size_t ws_size,
                              hipStream_t stream)
{
    const float* X = (const float*)d_in[0];
    const float* chang = (const float*)d_in[1];
    const float* kang = (const float*)d_in[2];
    const float* cent = (const float*)d_in[3];
    const float* kent = (const float*)d_in[4];
    float* out = (float*)d_out;

    size_t off = 0;
    auto alloc = [&](size_t bytes) -> char* {
        char* p = (char*)d_ws + off;
        off += (bytes + 255) & ~(size_t)255;
        return p;
    };
    float* bufT = (float*)alloc(2048 * 512 * 4);            // T0 fp32
    float* TtA = (float*)alloc(512 * 2048 * 4);             // fp32 pre-chrot
    float* Pa = (float*)alloc(8 * 512 * 512 * 4);           // ghat partials
    float* C128 = (float*)alloc(2 * 128 * 128 * 4);
    float* K16 = (float*)alloc(2 * 16 * 16 * 4);
    float* mag = (float*)alloc(8192 * 4);
    float* acc = (float*)alloc(8192 * 4);
    unsigned short* T0hi = (unsigned short*)alloc(512 * 2048 * 2);
    unsigned short* T0lo = (unsigned short*)alloc(512 * 2048 * 2);
    unsigned short* T1hi = (unsigned short*)alloc(512 * 2048 * 2);
    unsigned short* T1lo = (unsigned short*)alloc(512 * 2048 * 2);
    unsigned short* TPhi = (unsigned short*)alloc(512 * 2048 * 2);
    unsigned short* TPlo = (unsigned short*)alloc(512 * 2048 * 2);
    unsigned short* Ghi = (unsigned short*)alloc(512 * 512 * 2);
    unsigned short* Glo = (unsigned short*)alloc(512 * 512 * 2);
    unsigned short* Xhi = (unsigned short*)alloc(8192 * 512 * 2);
    unsigned short* Xlo = (unsigned short*)alloc(8192 * 512 * 2);
    unsigned short* ceHi = (unsigned short*)alloc(2048 * 2048 * 2);
    unsigned short* ceLo = (unsigned short*)alloc(2048 * 2048 * 2);
    unsigned short* keHi = (unsigned short*)alloc(2048 * 2048 * 2);
    unsigned short* keLo = (unsigned short*)alloc(2048 * 2048 * 2);
    (void)ws_size;

    // merged prep: ent convert (8192) + X convert (4096) + collapse (4096) + rots (64)
    prep_kernel<<<16448, 256, 0, stream>>>(X, chang, kang, cent, kent,
                                           ceHi, ceLo, keHi, keLo,
                                           Xhi, Xlo, mag, acc, bufT, C128, K16);
    transpose_convert_kernel<<<dim3(32, 8), 256, 0, stream>>>(bufT, K16 + 256, T0hi, T0lo); // +kr1

    // G1: kent @ T -> hi/lo
    gemm_hl_kernel<1><<<dim3(32, 8, 1), 256, 0, stream>>>(
        keHi, keLo, 2048, T0hi, T0lo, 2048, nullptr, T1hi, T1lo, nullptr, nullptr,
        nullptr, nullptr, 2048, 512, 2048);
    // G2: cent @ T -> fp32 TtA
    gemm_hl_kernel<0><<<dim3(32, 8, 1), 256, 0, stream>>>(
        ceHi, ceLo, 2048, T1hi, T1lo, 2048, TtA, nullptr, nullptr, nullptr, nullptr,
        nullptr, nullptr, 2048, 512, 2048);
    // ch1 + kr0 -> hi/lo
    chrot_t_kernel<<<512, 256, 0, stream>>>(C128 + 16384, K16, TtA, T0hi, T0lo);
    // G3: kent @ T -> hi/lo
    gemm_hl_kernel<1><<<dim3(32, 8, 1), 256, 0, stream>>>(
        keHi, keLo, 2048, T0hi, T0lo, 2048, nullptr, T1hi, T1lo, nullptr, nullptr,
        nullptr, nullptr, 2048, 512, 2048);
    // G4: cent @ T -> fp32 TtA
    gemm_hl_kernel<0><<<dim3(32, 8, 1), 256, 0, stream>>>(
        ceHi, ceLo, 2048, T1hi, T1lo, 2048, TtA, nullptr, nullptr, nullptr, nullptr,
        nullptr, nullptr, 2048, 512, 2048);
    // ch0 -> hi/lo
    chrot_t_kernel<<<512, 256, 0, stream>>>(C128, nullptr, TtA, T0hi, T0lo);
    // G5: cent @ T -> hi/lo + parity copy
    gemm_hl_kernel<2><<<dim3(32, 8, 1), 256, 0, stream>>>(
        ceHi, ceLo, 2048, T0hi, T0lo, 2048, nullptr, T1hi, T1lo, TPhi, TPlo,
        nullptr, nullptr, 2048, 512, 2048);
    // ghat: split-K=8 partials then reduce -> Ghi/Glo
    gemm_hl_kernel<3><<<dim3(8, 8, 8), 256, 0, stream>>>(
        T1hi, T1lo, 2048, TPhi, TPlo, 2048, Pa, nullptr, nullptr, nullptr, nullptr,
        nullptr, nullptr, 512, 512, 256);
    reduce_hl_kernel<<<256, 256, 0, stream>>>(Pa, 8, 512 * 512, Ghi, Glo);
    // final: fused X@G^T row-dot -> acc
    gemm_hl_kernel<4><<<dim3(128, 8, 1), 256, 0, stream>>>(
        Xhi, Xlo, 512, Ghi, Glo, 512, nullptr, nullptr, nullptr, nullptr, nullptr,
        X, acc, 8192, 512, 512);
    divide_kernel<<<32, 256, 0, stream>>>(acc, mag, out);
}